// Round 2
// baseline (655.978 us; speedup 1.0000x reference)
//
#include <hip/hip_runtime.h>

#define B_ 32
#define N_ 1009
#define C_ 768
#define H_ 12
#define D_ 64
#define M_ (B_*N_)          // 32288 tokens
#define MT_ 253             // ceil(M/128)
#define MPAD_ (MT_*128)     // 32384
#define NKV_ 1024           // padded sequence length for q/k/v storage

typedef __attribute__((ext_vector_type(4))) float f32x4;
typedef __attribute__((ext_vector_type(8))) short s16x8;

__device__ __forceinline__ unsigned short f2bf(float f) {
  union { float f; unsigned u; } x; x.f = f;
  unsigned r = x.u + 0x7fffu + ((x.u >> 16) & 1u);
  return (unsigned short)(r >> 16);
}

__device__ __forceinline__ f32x4 mfma16(s16x8 a, s16x8 b, f32x4 c) {
  return __builtin_amdgcn_mfma_f32_16x16x32_bf16(a, b, c, 0, 0, 0);
}

__device__ __forceinline__ void async16(const void* g, void* l) {
  __builtin_amdgcn_global_load_lds((const __attribute__((address_space(1))) void*)g,
                                   (__attribute__((address_space(3))) void*)l, 16, 0, 0);
}

// ---------------- x fp32 -> bf16 (pad rows zeroed) ----------------
__global__ void convert_x(const float* __restrict__ x, unsigned short* __restrict__ xb) {
  const long e = ((long)blockIdx.x * 256 + threadIdx.x) * 8;
  const long row = e / 768;
  s16x8 v;
  if (row < M_) {
#pragma unroll
    for (int j = 0; j < 8; ++j) v[j] = (short)f2bf(x[e + j]);
  } else {
    v = (s16x8){0,0,0,0,0,0,0,0};
  }
  *(s16x8*)&xb[e] = v;
}

// ---------------- W [R][C] fp32 -> W^T [C][R] bf16 ----------------
__global__ void transpose_convert(const float* __restrict__ in, unsigned short* __restrict__ out,
                                  int R, int Ccols) {
  __shared__ float tile[64][65];
  const int tc = blockIdx.x * 64, tr = blockIdx.y * 64;
#pragma unroll
  for (int i = 0; i < 16; ++i) {
    const int e = i * 256 + threadIdx.x;
    const int r = e >> 6, c = e & 63;
    tile[r][c] = in[(long)(tr + r) * Ccols + tc + c];
  }
  __syncthreads();
#pragma unroll
  for (int i = 0; i < 16; ++i) {
    const int e = i * 256 + threadIdx.x;
    const int c = e >> 6, r = e & 63;
    out[(long)(tc + c) * R + tr + r] = f2bf(tile[r][c]);
  }
}

// ---------------- zero the padding tokens 1009..1023 of K and V^T ----------------
__global__ void zero_pad(unsigned short* __restrict__ kb, unsigned short* __restrict__ vt) {
  const int t = blockIdx.x * 256 + threadIdx.x;
  if (t >= 368640) return;                       // 384*15*64 == 24576*15
  const int d = t & 63;
  const int r = t >> 6;                          // [0,5760)
  const int bh = r / 15, tok = 1009 + (r - bh * 15);
  kb[(((long)bh << 10) + tok) * 64 + d] = 0;     // K: [BH][1024][64]
  const int c = t % 15, row = t / 15;            // row < 24576
  vt[((long)row << 10) + 1009 + c] = 0;          // V^T: [BH*64 rows][1024]
}

// ---------------- GEMM: A[M x 768] bf16 row-major, Bt[N x 768] bf16 (B^T) ----------------
// MODE 0: qkv epilogue (q,k row-major [BH][1024][64]; V TRANSPOSED [BH][64][1024]);
// MODE 1: fp32 out + bias
template<int MODE>
__global__ __launch_bounds__(256, 2)
void gemm_bt(const unsigned short* __restrict__ A,
             const unsigned short* __restrict__ Bt,
             const float* __restrict__ bias,
             unsigned short* __restrict__ qo,
             unsigned short* __restrict__ ko,
             unsigned short* __restrict__ vo,
             float* __restrict__ fo) {
  __shared__ __align__(16) unsigned short As[128 * 32];
  __shared__ __align__(16) unsigned short Bs[128 * 32];
  const int tid = threadIdx.x;
  const int lane = tid & 63;
  const int wv = tid >> 6;
  const int bm = blockIdx.x % MT_;
  const int bn = blockIdx.x / MT_;
  const int row0 = bm * 128;
  const int col0 = bn * 128;
  const int wr = (wv >> 1) * 64;
  const int wc = (wv & 1) * 64;

  f32x4 acc[4][4] = {};
  for (int kt = 0; kt < 768; kt += 32) {
#pragma unroll
    for (int c = 0; c < 2; ++c) {
      const int lds_byte = c * 4096 + wv * 1024;   // wave-uniform LDS base
      const int elem = (lds_byte >> 1) + lane * 8; // per-lane element
      const int row = elem >> 5;
      const int kk = elem & 31;
      async16(A + (long)(row0 + row) * 768 + kt + kk, (char*)As + lds_byte);
      async16(Bt + (long)(col0 + row) * 768 + kt + kk, (char*)Bs + lds_byte);
    }
    __syncthreads();
    s16x8 af[4], bfr[4];
#pragma unroll
    for (int m = 0; m < 4; ++m)
      af[m] = *(const s16x8*)&As[(wr + m * 16 + (lane & 15)) * 32 + (lane >> 4) * 8];
#pragma unroll
    for (int n = 0; n < 4; ++n)
      bfr[n] = *(const s16x8*)&Bs[(wc + n * 16 + (lane & 15)) * 32 + (lane >> 4) * 8];
#pragma unroll
    for (int m = 0; m < 4; ++m)
#pragma unroll
      for (int n = 0; n < 4; ++n)
        acc[m][n] = mfma16(af[m], bfr[n], acc[m][n]);
    __syncthreads();
  }

#pragma unroll
  for (int m = 0; m < 4; ++m) {
#pragma unroll
    for (int j = 0; j < 4; ++j) {
      const int grow = row0 + wr + m * 16 + (lane >> 4) * 4 + j;
      if (grow < M_) {
        if (MODE == 0) {
          const int b = grow / N_;
          const int ntok = grow - b * N_;
#pragma unroll
          for (int n = 0; n < 4; ++n) {
            const int col = col0 + wc + n * 16 + (lane & 15);
            const float val = acc[m][n][j] + bias[col];
            const int which = col / 768;
            const int rem = col - which * 768;
            const int h = rem >> 6, d = rem & 63;
            const long bh = (long)b * H_ + h;
            if (which == 2) {
              // V stored transposed: [BH][64 d][1024 tok]
              vo[((bh * 64 + d) << 10) + ntok] = f2bf(val);
            } else {
              unsigned short* dst = which ? ko : qo;
              dst[((bh << 10) + ntok) * 64 + d] = f2bf(val);
            }
          }
        } else {
#pragma unroll
          for (int n = 0; n < 4; ++n) {
            const int col = col0 + wc + n * 16 + (lane & 15);
            fo[(long)grow * 768 + col] = acc[m][n][j] + bias[col];
          }
        }
      }
    }
  }
}

// ---------------- prompt segment: out[n=0] = v[n=0] (V^T layout) ----------------
__global__ void misc_copy(const unsigned short* __restrict__ vt, unsigned short* __restrict__ og) {
  const int t = blockIdx.x * 256 + threadIdx.x;
  if (t >= B_ * H_ * D_) return;
  const int d = t & 63;
  const int bh = t >> 6;
  const int b = bh / H_, h = bh - b * H_;
  og[((long)b * N_) * 768 + h * 64 + d] = vt[(((long)bh << 6) + d) << 10];
}

// ---------------- flash attention: block = (b, h, 64-query tile), KVBLK=128 ----------------
// K [BH][1024][64] row-major; V^T [BH][64][1024]. Staged async into XOR-swizzled LDS
// (K: 8 chunks/row ^row&7; V^T/Ps: 16 chunks/row ^row&15) via pre-swizzled global src.
// Double-buffered 128-key tiles, counted vmcnt, defer-max (THR=8 in ln-domain).
__global__ __launch_bounds__(256, 2)
void attn_kernel(const unsigned short* __restrict__ qg,
                 const unsigned short* __restrict__ kg,
                 const unsigned short* __restrict__ vtg,
                 unsigned short* __restrict__ og) {
  __shared__ __align__(16) unsigned short Ks[2][128 * 64];   // [key][d]
  __shared__ __align__(16) unsigned short Vts[2][64 * 128];  // [d][key]
  __shared__ __align__(16) unsigned short Ps[64 * 128];      // [qrow][key]

  // XCD-chunked swizzle: all 16 tiles of a (b,h) stay on one XCD's L2 (grid 6144 % 8 == 0)
  const int bid = blockIdx.x;
  const int swz = (bid & 7) * 768 + (bid >> 3);
  const int tile = swz & 15;
  const int bh = swz >> 4;
  const int b = bh / H_;
  const int h = bh - b * H_;
  int qbase, qend, kstart, ktiles, kend;
  if (tile < 7) { qbase = 1 + 64 * tile;       qend = 433;  kstart = 1; ktiles = 4; kend = 433; }
  else          { qbase = 433 + 64 * (tile-7); qend = 1009; kstart = 0; ktiles = 8; kend = 1009; }
  const long base  = (long)bh << 10;   // K/Q row base
  const long vbase = (long)bh << 6;    // V^T row base (d-major rows)
  const int tid = threadIdx.x, lane = tid & 63, wv = tid >> 6;

  // Q fragments (wave wv owns q rows [wv*16, wv*16+16))
  s16x8 qa[2];
  {
    const unsigned short* qp = qg + (base + qbase + wv * 16 + (lane & 15)) * 64;
    qa[0] = *(const s16x8*)(qp + (lane >> 4) * 8);
    qa[1] = *(const s16x8*)(qp + 32 + (lane >> 4) * 8);
  }
  asm volatile("s_waitcnt vmcnt(0)" ::: "memory");  // Q landed; vmem counter now clean

  f32x4 o[4] = {};
  float mrow[4] = {-1e30f, -1e30f, -1e30f, -1e30f};
  float lrow[4] = {0.f, 0.f, 0.f, 0.f};

  // stage one 128-key tile of K and V^T (8 async16/thread), pre-swizzled global src
  auto stage = [&](int bufsel, int kb0) {
#pragma unroll
    for (int it = 0; it < 4; ++it) {
      const int g = it * 256 + wv * 64 + lane;           // 16B granule 0..1023
      const int ldsoff = (it * 256 + wv * 64) * 16;      // wave-uniform dest base
      const int krl = g >> 3;                            // K row (8 granules/row)
      const int kc = (g & 7) ^ (krl & 7);
      async16(kg + ((base + kb0 + krl) << 6) + kc * 8, (char*)&Ks[bufsel][0] + ldsoff);
      const int vrl = g >> 4;                            // V^T row (16 granules/row)
      const int vc = (g & 15) ^ (vrl & 15);
      async16(vtg + ((vbase + vrl) << 10) + kb0 + vc * 8, (char*)&Vts[bufsel][0] + ldsoff);
    }
  };

  stage(0, kstart);
  for (int kt = 0; kt < ktiles; ++kt) {
    const int buf = kt & 1;
    const int kbase0 = kstart + 128 * kt;
    if (kt + 1 < ktiles) {
      stage(buf ^ 1, kbase0 + 128);
      asm volatile("s_waitcnt vmcnt(8)" ::: "memory");   // current tile's 8 DMAs landed
    } else {
      asm volatile("s_waitcnt vmcnt(0)" ::: "memory");
    }
    __builtin_amdgcn_s_barrier();

    // S = Q K^T * scale  (C layout: col=key=lane&15 within frag, row=(lane>>4)*4+reg)
    f32x4 s[8];
    __builtin_amdgcn_s_setprio(1);
#pragma unroll
    for (int n = 0; n < 8; ++n) {
      const int krow = n * 16 + (lane & 15);
      const int r7 = krow & 7;
      f32x4 a = {};
      a = mfma16(qa[0], *(const s16x8*)&Ks[buf][krow * 64 + ((((lane >> 4))     ^ r7) << 3)], a);
      a = mfma16(qa[1], *(const s16x8*)&Ks[buf][krow * 64 + (((4 + (lane >> 4)) ^ r7) << 3)], a);
      const bool bad = (kbase0 + krow) >= kend;
#pragma unroll
      for (int j = 0; j < 4; ++j)
        s[n][j] = bad ? -1e30f : a[j] * 0.125f;
    }
    __builtin_amdgcn_s_setprio(0);

    // online softmax per q-row (reduce across the 16-lane column group); defer-max THR=8
#pragma unroll
    for (int j = 0; j < 4; ++j) {
      float rmax = fmaxf(fmaxf(fmaxf(s[0][j], s[1][j]), fmaxf(s[2][j], s[3][j])),
                         fmaxf(fmaxf(s[4][j], s[5][j]), fmaxf(s[6][j], s[7][j])));
      rmax = fmaxf(rmax, __shfl_xor(rmax, 1));
      rmax = fmaxf(rmax, __shfl_xor(rmax, 2));
      rmax = fmaxf(rmax, __shfl_xor(rmax, 4));
      rmax = fmaxf(rmax, __shfl_xor(rmax, 8));
      float mnew;
      if (__all(rmax <= mrow[j] + 8.f)) {
        mnew = mrow[j];                       // defer: no rescale, P bounded by e^8
      } else {
        mnew = fmaxf(mrow[j], rmax);
        const float corr = __expf(mrow[j] - mnew);
        mrow[j] = mnew;
        lrow[j] *= corr;
#pragma unroll
        for (int f = 0; f < 4; ++f) o[f][j] *= corr;
      }
      const int prow = wv * 16 + (lane >> 4) * 4 + j;
      const int p15 = prow & 15;
      float ps = 0.f;
#pragma unroll
      for (int n = 0; n < 8; ++n) {
        const float pv = __expf(s[n][j] - mnew);
        ps += pv;
        const int col = n * 16 + (lane & 15);
        Ps[prow * 128 + (((col >> 3) ^ p15) << 3) + (col & 7)] = f2bf(pv);
      }
      ps += __shfl_xor(ps, 1);
      ps += __shfl_xor(ps, 2);
      ps += __shfl_xor(ps, 4);
      ps += __shfl_xor(ps, 8);
      lrow[j] += ps;
    }

    // O += P V  (pa: this wave's private Ps rows; vb: V^T rows, both swizzle-read)
    s16x8 pa[4];
    const int prowr = wv * 16 + (lane & 15);
    const int pr15 = prowr & 15;
#pragma unroll
    for (int kf = 0; kf < 4; ++kf)
      pa[kf] = *(const s16x8*)&Ps[prowr * 128 + (((kf * 4 + (lane >> 4)) ^ pr15) << 3)];
    __builtin_amdgcn_s_setprio(1);
#pragma unroll
    for (int f = 0; f < 4; ++f) {
      const int vrow = f * 16 + (lane & 15);
      const int v15 = vrow & 15;
#pragma unroll
      for (int kf = 0; kf < 4; ++kf) {
        const s16x8 vb = *(const s16x8*)&Vts[buf][vrow * 128 + (((kf * 4 + (lane >> 4)) ^ v15) << 3)];
        o[f] = mfma16(pa[kf], vb, o[f]);
      }
    }
    __builtin_amdgcn_s_setprio(0);

    // drain our ds_reads before anyone overwrites this buffer next iteration
    asm volatile("s_waitcnt lgkmcnt(0)" ::: "memory");
    __builtin_amdgcn_s_barrier();
  }

#pragma unroll
  for (int j = 0; j < 4; ++j) {
    const int qrow = qbase + wv * 16 + (lane >> 4) * 4 + j;
    if (qrow < qend) {
      const float inv = 1.0f / lrow[j];
      const long rowoff = ((long)b * N_ + qrow) * 768 + h * 64;
#pragma unroll
      for (int f = 0; f < 4; ++f)
        og[rowoff + f * 16 + (lane & 15)] = f2bf(o[f][j] * inv);
    }
  }
}

extern "C" void kernel_launch(void* const* d_in, const int* in_sizes, int n_in,
                              void* d_out, int out_size, void* d_ws, size_t ws_size,
                              hipStream_t stream) {
  const float* x      = (const float*)d_in[0];
  const float* W_qkv  = (const float*)d_in[1];
  const float* b_qkv  = (const float*)d_in[2];
  const float* W_proj = (const float*)d_in[3];
  const float* b_proj = (const float*)d_in[4];
  float* out = (float*)d_out;

  unsigned short* ws = (unsigned short*)d_ws;
  unsigned short* wqkvT  = ws;                                  // [2304][768] bf16
  unsigned short* wprojT = wqkvT + (long)2304 * 768;            // [768][768] bf16
  unsigned short* qb = wprojT + (long)768 * 768;                // [B][H][1024][64] bf16
  const long kvsz = (long)B_ * H_ * NKV_ * D_;
  unsigned short* kb = qb + kvsz;                               // [B][H][1024][64] bf16
  unsigned short* vb = kb + kvsz;                               // V^T: [B][H][64][1024] bf16
  unsigned short* xb = vb + kvsz;                               // [MPAD][768] bf16
  unsigned short* attnout = xb;  // aliased: xb dead after QKV GEMM (stream-ordered)

  zero_pad<<<1440, 256, 0, stream>>>(kb, vb);
  convert_x<<<12144, 256, 0, stream>>>(x, xb);
  transpose_convert<<<dim3(2304 / 64, 768 / 64), 256, 0, stream>>>(W_qkv, wqkvT, 768, 2304);
  transpose_convert<<<dim3(768 / 64, 768 / 64), 256, 0, stream>>>(W_proj, wprojT, 768, 768);
  gemm_bt<0><<<MT_ * 18, 256, 0, stream>>>(xb, wqkvT, b_qkv, qb, kb, vb, nullptr);
  misc_copy<<<96, 256, 0, stream>>>(vb, attnout);
  attn_kernel<<<B_ * H_ * 16, 256, 0, stream>>>(qb, kb, vb, attnout);
  gemm_bt<1><<<MT_ * 6, 256, 0, stream>>>(attnout, wprojT, b_proj, nullptr, nullptr, nullptr, out);
}

// Round 3
// 562.947 us; speedup vs baseline: 1.1653x; 1.1653x over previous
//
#include <hip/hip_runtime.h>

#define B_ 32
#define N_ 1009
#define C_ 768
#define H_ 12
#define D_ 64
#define M_ (B_*N_)          // 32288 tokens
#define MT_ 253             // ceil(M/128)
#define MPAD_ (MT_*128)     // 32384
#define NKV_ 1024           // padded sequence length for q/k/v storage

typedef __attribute__((ext_vector_type(4))) float f32x4;
typedef __attribute__((ext_vector_type(8))) short s16x8;

__device__ __forceinline__ unsigned short f2bf(float f) {
  union { float f; unsigned u; } x; x.f = f;
  unsigned r = x.u + 0x7fffu + ((x.u >> 16) & 1u);
  return (unsigned short)(r >> 16);
}

__device__ __forceinline__ f32x4 mfma16(s16x8 a, s16x8 b, f32x4 c) {
  return __builtin_amdgcn_mfma_f32_16x16x32_bf16(a, b, c, 0, 0, 0);
}

__device__ __forceinline__ void async16(const void* g, void* l) {
  __builtin_amdgcn_global_load_lds((const __attribute__((address_space(1))) void*)g,
                                   (__attribute__((address_space(3))) void*)l, 16, 0, 0);
}

// ---------------- x fp32 -> bf16 (pad rows zeroed) ----------------
__global__ void convert_x(const float* __restrict__ x, unsigned short* __restrict__ xb) {
  const long e = ((long)blockIdx.x * 256 + threadIdx.x) * 8;
  const long row = e / 768;
  s16x8 v;
  if (row < M_) {
#pragma unroll
    for (int j = 0; j < 8; ++j) v[j] = (short)f2bf(x[e + j]);
  } else {
    v = (s16x8){0,0,0,0,0,0,0,0};
  }
  *(s16x8*)&xb[e] = v;
}

// ---------------- W [R][C] fp32 -> W^T [C][R] bf16 ----------------
__global__ void transpose_convert(const float* __restrict__ in, unsigned short* __restrict__ out,
                                  int R, int Ccols) {
  __shared__ float tile[64][65];
  const int tc = blockIdx.x * 64, tr = blockIdx.y * 64;
#pragma unroll
  for (int i = 0; i < 16; ++i) {
    const int e = i * 256 + threadIdx.x;
    const int r = e >> 6, c = e & 63;
    tile[r][c] = in[(long)(tr + r) * Ccols + tc + c];
  }
  __syncthreads();
#pragma unroll
  for (int i = 0; i < 16; ++i) {
    const int e = i * 256 + threadIdx.x;
    const int c = e >> 6, r = e & 63;
    out[(long)(tc + c) * R + tr + r] = f2bf(tile[r][c]);
  }
}

// ---------------- zero the padding tokens 1009..1023 of K and V^T ----------------
__global__ void zero_pad(unsigned short* __restrict__ kb, unsigned short* __restrict__ vt) {
  const int t = blockIdx.x * 256 + threadIdx.x;
  if (t >= 368640) return;                       // 384*15*64 == 24576*15
  const int d = t & 63;
  const int r = t >> 6;                          // [0,5760)
  const int bh = r / 15, tok = 1009 + (r - bh * 15);
  kb[(((long)bh << 10) + tok) * 64 + d] = 0;     // K: [BH][1024][64]
  const int c = t % 15, row = t / 15;            // row < 24576
  vt[((long)row << 10) + 1009 + c] = 0;          // V^T: [BH*64 rows][1024]
}

// ---------------- GEMM: A[M x 768] bf16 row-major, Bt[N x 768] bf16 (B^T) ----------------
// MODE 0: qkv epilogue. q,k scattered row-major [BH][1024][64] (lane-consecutive in d);
//   V-blocks (col0>=1536) transpose 128x128 through LDS then write V^T [BH][64][1024]
//   with lane-consecutive token addresses (coalesced).
// MODE 1: fp32 out + bias.
template<int MODE>
__global__ __launch_bounds__(256, 2)
void gemm_bt(const unsigned short* __restrict__ A,
             const unsigned short* __restrict__ Bt,
             const float* __restrict__ bias,
             unsigned short* __restrict__ qo,
             unsigned short* __restrict__ ko,
             unsigned short* __restrict__ vo,
             float* __restrict__ fo) {
  __shared__ __align__(16) unsigned short smem[128 * 136];  // As(4096) | Bs(4096); V-transpose tile reuse
  unsigned short* const As = smem;
  unsigned short* const Bs = smem + 4096;
  const int tid = threadIdx.x;
  const int lane = tid & 63;
  const int wv = tid >> 6;
  const int bm = blockIdx.x % MT_;
  const int bn = blockIdx.x / MT_;
  const int row0 = bm * 128;
  const int col0 = bn * 128;
  const int wr = (wv >> 1) * 64;
  const int wc = (wv & 1) * 64;

  f32x4 acc[4][4] = {};
  for (int kt = 0; kt < 768; kt += 32) {
#pragma unroll
    for (int c = 0; c < 2; ++c) {
      const int lds_byte = c * 4096 + wv * 1024;   // wave-uniform LDS base
      const int elem = (lds_byte >> 1) + lane * 8; // per-lane element
      const int row = elem >> 5;
      const int kk = elem & 31;
      async16(A + (long)(row0 + row) * 768 + kt + kk, (char*)As + lds_byte);
      async16(Bt + (long)(col0 + row) * 768 + kt + kk, (char*)Bs + lds_byte);
    }
    __syncthreads();
    s16x8 af[4], bfr[4];
#pragma unroll
    for (int m = 0; m < 4; ++m)
      af[m] = *(const s16x8*)&As[(wr + m * 16 + (lane & 15)) * 32 + (lane >> 4) * 8];
#pragma unroll
    for (int n = 0; n < 4; ++n)
      bfr[n] = *(const s16x8*)&Bs[(wc + n * 16 + (lane & 15)) * 32 + (lane >> 4) * 8];
#pragma unroll
    for (int m = 0; m < 4; ++m)
#pragma unroll
      for (int n = 0; n < 4; ++n)
        acc[m][n] = mfma16(af[m], bfr[n], acc[m][n]);
    __syncthreads();
  }

  if (MODE == 0 && col0 >= 1536) {
    // ---- V path: stage transposed tile [d_local 0..127][tok 0..127] in LDS ----
    // (K-loop ended with __syncthreads(); As/Bs dead, smem reusable immediately)
#pragma unroll
    for (int m = 0; m < 4; ++m)
#pragma unroll
      for (int j = 0; j < 4; ++j)
#pragma unroll
        for (int n = 0; n < 4; ++n) {
          const int dl = wc + n * 16 + (lane & 15);
          const int tk = wr + m * 16 + (lane >> 4) * 4 + j;
          smem[dl * 136 + tk] = f2bf(acc[m][n][j] + bias[col0 + dl]);
        }
    __syncthreads();
    const int h0 = (col0 - 1536) >> 6;
    const int b0 = row0 / N_;
    const int split = (b0 + 1) * N_ - row0;   // block tokens [0,split) belong to batch b0
#pragma unroll
    for (int it = 0; it < 8; ++it) {
      const int g = it * 256 + tid;
      const int dl = g >> 4;
      const int t8 = (g & 15) * 8;
      const s16x8 vv = *(const s16x8*)&smem[dl * 136 + t8];   // 16B aligned (136*2=272=17*16)
      const int hh = h0 + (dl >> 6), dd = dl & 63;
#pragma unroll
      for (int jj = 0; jj < 8; ++jj) {
        const int tkb = t8 + jj;
        const int grow = row0 + tkb;
        if (grow < M_) {
          const int bb = (tkb < split) ? b0 : b0 + 1;
          const int ntok = grow - bb * N_;
          vo[(((((long)bb * H_ + hh) << 6) + dd) << 10) + ntok] = (unsigned short)vv[jj];
        }
      }
    }
    return;
  }

#pragma unroll
  for (int m = 0; m < 4; ++m) {
#pragma unroll
    for (int j = 0; j < 4; ++j) {
      const int grow = row0 + wr + m * 16 + (lane >> 4) * 4 + j;
      if (grow < M_) {
        if (MODE == 0) {
          const int b = grow / N_;
          const int ntok = grow - b * N_;
#pragma unroll
          for (int n = 0; n < 4; ++n) {
            const int col = col0 + wc + n * 16 + (lane & 15);
            const float val = acc[m][n][j] + bias[col];
            const int which = col >= 768;       // 0: q, 1: k (V handled above)
            const int rem = col - which * 768;
            const int h = rem >> 6, d = rem & 63;
            const long bh = (long)b * H_ + h;
            unsigned short* dst = which ? ko : qo;
            dst[((bh << 10) + ntok) * 64 + d] = f2bf(val);
          }
        } else {
#pragma unroll
          for (int n = 0; n < 4; ++n) {
            const int col = col0 + wc + n * 16 + (lane & 15);
            fo[(long)grow * 768 + col] = acc[m][n][j] + bias[col];
          }
        }
      }
    }
  }
}

// ---------------- prompt segment: out[n=0] = v[n=0] (V^T layout) ----------------
__global__ void misc_copy(const unsigned short* __restrict__ vt, unsigned short* __restrict__ og) {
  const int t = blockIdx.x * 256 + threadIdx.x;
  if (t >= B_ * H_ * D_) return;
  const int d = t & 63;
  const int bh = t >> 6;
  const int b = bh / H_, h = bh - b * H_;
  og[((long)b * N_) * 768 + h * 64 + d] = vt[(((long)bh << 6) + d) << 10];
}

// ---------------- flash attention: block = (b, h, 64-query tile), KVBLK=64 ----------------
// K [BH][1024][64] row-major; V^T [BH][64][1024]. Both staged async (global_load_lds)
// into XOR-swizzled LDS (chunk ^= row&7 per 16B chunk) via pre-swizzled global src.
// Double-buffered tiles with counted vmcnt + raw barriers; Ps swizzled.
__global__ __launch_bounds__(256, 4)
void attn_kernel(const unsigned short* __restrict__ qg,
                 const unsigned short* __restrict__ kg,
                 const unsigned short* __restrict__ vtg,
                 unsigned short* __restrict__ og) {
  __shared__ __align__(16) unsigned short Ks[2][64 * 64];
  __shared__ __align__(16) unsigned short Vts[2][64 * 64];
  __shared__ __align__(16) unsigned short Ps[64 * 64];

  // XCD-chunked swizzle: all 16 tiles of a (b,h) stay on one XCD's L2 (grid 6144 % 8 == 0)
  const int bid = blockIdx.x;
  const int swz = (bid & 7) * 768 + (bid >> 3);
  const int tile = swz & 15;
  const int bh = swz >> 4;
  const int b = bh / H_;
  const int h = bh - b * H_;
  int qbase, qend, kstart, ktiles, kend;
  if (tile < 7) { qbase = 1 + 64 * tile;       qend = 433;  kstart = 1; ktiles = 7;  kend = 433; }
  else          { qbase = 433 + 64 * (tile-7); qend = 1009; kstart = 0; ktiles = 16; kend = 1009; }
  const long base  = (long)bh << 10;   // K/Q row base
  const long vbase = (long)bh << 6;    // V^T row base (d-major rows)
  const int tid = threadIdx.x, lane = tid & 63, wv = tid >> 6;

  // Q fragments (wave wv owns q rows [wv*16, wv*16+16))
  s16x8 qa[2];
  {
    const unsigned short* qp = qg + (base + qbase + wv * 16 + (lane & 15)) * 64;
    qa[0] = *(const s16x8*)(qp + (lane >> 4) * 8);
    qa[1] = *(const s16x8*)(qp + 32 + (lane >> 4) * 8);
  }
  asm volatile("s_waitcnt vmcnt(0)" ::: "memory");  // Q landed; vmem counter now clean

  f32x4 o[4] = {};
  float mrow[4] = {-1e30f, -1e30f, -1e30f, -1e30f};
  float lrow[4] = {0.f, 0.f, 0.f, 0.f};

  // stage one 64-key tile of K and V^T: linear LDS dest, swizzled global src (4 async16/thread)
  auto stage = [&](int bufsel, int kb0) {
#pragma unroll
    for (int it = 0; it < 2; ++it) {
      const int ldsoff = (it * 256 + wv * 64) * 16;      // wave-uniform dest base
      const int g = it * 256 + wv * 64 + lane;           // this lane's 16B granule
      const int rl = g >> 3;                             // LDS row (key for K, d for V^T)
      const int cs = (g & 7) ^ (rl & 7);                 // pre-swizzled source chunk
      async16(kg + ((base + kb0 + rl) << 6) + cs * 8, (char*)&Ks[bufsel][0] + ldsoff);
      async16(vtg + ((vbase + rl) << 10) + kb0 + cs * 8, (char*)&Vts[bufsel][0] + ldsoff);
    }
  };

  stage(0, kstart);
  for (int kt = 0; kt < ktiles; ++kt) {
    const int buf = kt & 1;
    const int kbase0 = kstart + 64 * kt;
    if (kt + 1 < ktiles) {
      stage(buf ^ 1, kbase0 + 64);
      asm volatile("s_waitcnt vmcnt(4)" ::: "memory");   // current tile's 4 DMAs landed
    } else {
      asm volatile("s_waitcnt vmcnt(0)" ::: "memory");
    }
    __builtin_amdgcn_s_barrier();

    // S = Q K^T * scale  (C layout: col=key=lane&15 within frag, row=(lane>>4)*4+reg)
    f32x4 s[4];
    __builtin_amdgcn_s_setprio(1);
#pragma unroll
    for (int n = 0; n < 4; ++n) {
      const int krow = n * 16 + (lane & 15);
      const int r7 = krow & 7;
      f32x4 a = {};
      a = mfma16(qa[0], *(const s16x8*)&Ks[buf][krow * 64 + ((((lane >> 4))     ^ r7) << 3)], a);
      a = mfma16(qa[1], *(const s16x8*)&Ks[buf][krow * 64 + (((4 + (lane >> 4)) ^ r7) << 3)], a);
      const bool bad = (kbase0 + krow) >= kend;
#pragma unroll
      for (int j = 0; j < 4; ++j)
        s[n][j] = bad ? -1e30f : a[j] * 0.125f;
    }
    __builtin_amdgcn_s_setprio(0);

    // online softmax per q-row (reduce across the 16-lane column group)
#pragma unroll
    for (int j = 0; j < 4; ++j) {
      float rmax = fmaxf(fmaxf(s[0][j], s[1][j]), fmaxf(s[2][j], s[3][j]));
      rmax = fmaxf(rmax, __shfl_xor(rmax, 1));
      rmax = fmaxf(rmax, __shfl_xor(rmax, 2));
      rmax = fmaxf(rmax, __shfl_xor(rmax, 4));
      rmax = fmaxf(rmax, __shfl_xor(rmax, 8));
      const float mnew = fmaxf(mrow[j], rmax);
      const float corr = __expf(mrow[j] - mnew);
      mrow[j] = mnew;
      const int prow = wv * 16 + (lane >> 4) * 4 + j;
      const int p7 = prow & 7;
      float ps = 0.f;
#pragma unroll
      for (int n = 0; n < 4; ++n) {
        const float pv = __expf(s[n][j] - mnew);
        ps += pv;
        const int col = n * 16 + (lane & 15);
        Ps[prow * 64 + (((col >> 3) ^ p7) << 3) + (col & 7)] = f2bf(pv);
      }
      ps += __shfl_xor(ps, 1);
      ps += __shfl_xor(ps, 2);
      ps += __shfl_xor(ps, 4);
      ps += __shfl_xor(ps, 8);
      lrow[j] = lrow[j] * corr + ps;
#pragma unroll
      for (int f = 0; f < 4; ++f) o[f][j] *= corr;
    }

    // O += P V  (pa: this wave's private Ps rows; vb: V^T rows, both swizzle-read)
    s16x8 pa[2];
    const int prowr = wv * 16 + (lane & 15);
    const int pr7 = prowr & 7;
#pragma unroll
    for (int kf = 0; kf < 2; ++kf)
      pa[kf] = *(const s16x8*)&Ps[prowr * 64 + (((kf * 4 + (lane >> 4)) ^ pr7) << 3)];
    __builtin_amdgcn_s_setprio(1);
#pragma unroll
    for (int f = 0; f < 4; ++f) {
      const int vrow = f * 16 + (lane & 15);
      const int v7 = vrow & 7;
#pragma unroll
      for (int kf = 0; kf < 2; ++kf) {
        const s16x8 vb = *(const s16x8*)&Vts[buf][vrow * 64 + (((kf * 4 + (lane >> 4)) ^ v7) << 3)];
        o[f] = mfma16(pa[kf], vb, o[f]);
      }
    }
    __builtin_amdgcn_s_setprio(0);

    // drain our ds_reads before anyone overwrites this buffer next iteration
    asm volatile("s_waitcnt lgkmcnt(0)" ::: "memory");
    __builtin_amdgcn_s_barrier();
  }

#pragma unroll
  for (int j = 0; j < 4; ++j) {
    const int qrow = qbase + wv * 16 + (lane >> 4) * 4 + j;
    if (qrow < qend) {
      const float inv = 1.0f / lrow[j];
      const long rowoff = ((long)b * N_ + qrow) * 768 + h * 64;
#pragma unroll
      for (int f = 0; f < 4; ++f)
        og[rowoff + f * 16 + (lane & 15)] = f2bf(o[f][j] * inv);
    }
  }
}

extern "C" void kernel_launch(void* const* d_in, const int* in_sizes, int n_in,
                              void* d_out, int out_size, void* d_ws, size_t ws_size,
                              hipStream_t stream) {
  const float* x      = (const float*)d_in[0];
  const float* W_qkv  = (const float*)d_in[1];
  const float* b_qkv  = (const float*)d_in[2];
  const float* W_proj = (const float*)d_in[3];
  const float* b_proj = (const float*)d_in[4];
  float* out = (float*)d_out;

  unsigned short* ws = (unsigned short*)d_ws;
  unsigned short* wqkvT  = ws;                                  // [2304][768] bf16
  unsigned short* wprojT = wqkvT + (long)2304 * 768;            // [768][768] bf16
  unsigned short* qb = wprojT + (long)768 * 768;                // [B][H][1024][64] bf16
  const long kvsz = (long)B_ * H_ * NKV_ * D_;
  unsigned short* kb = qb + kvsz;                               // [B][H][1024][64] bf16
  unsigned short* vb = kb + kvsz;                               // V^T: [B][H][64][1024] bf16
  unsigned short* xb = vb + kvsz;                               // [MPAD][768] bf16
  unsigned short* attnout = xb;  // aliased: xb dead after QKV GEMM (stream-ordered)

  zero_pad<<<1440, 256, 0, stream>>>(kb, vb);
  convert_x<<<12144, 256, 0, stream>>>(x, xb);
  transpose_convert<<<dim3(2304 / 64, 768 / 64), 256, 0, stream>>>(W_qkv, wqkvT, 768, 2304);
  transpose_convert<<<dim3(768 / 64, 768 / 64), 256, 0, stream>>>(W_proj, wprojT, 768, 768);
  gemm_bt<0><<<MT_ * 18, 256, 0, stream>>>(xb, wqkvT, b_qkv, qb, kb, vb, nullptr);
  misc_copy<<<96, 256, 0, stream>>>(vb, attnout);
  attn_kernel<<<B_ * H_ * 16, 256, 0, stream>>>(qb, kb, vb, attnout);
  gemm_bt<1><<<MT_ * 6, 256, 0, stream>>>(attnout, wprojT, b_proj, nullptr, nullptr, nullptr, out);
}

// Round 4
// 458.113 us; speedup vs baseline: 1.4319x; 1.2288x over previous
//
#include <hip/hip_runtime.h>

#define B_ 32
#define N_ 1009
#define C_ 768
#define H_ 12
#define D_ 64
#define M_ (B_*N_)          // 32288 tokens
#define MT_ 253             // ceil(M/128)
#define MPAD_ (MT_*128)     // 32384
#define NKV_ 1024           // padded sequence length for q/k/v storage

typedef __attribute__((ext_vector_type(4))) float f32x4;
typedef __attribute__((ext_vector_type(8))) short s16x8;

__device__ __forceinline__ unsigned short f2bf(float f) {
  union { float f; unsigned u; } x; x.f = f;
  unsigned r = x.u + 0x7fffu + ((x.u >> 16) & 1u);
  return (unsigned short)(r >> 16);
}

__device__ __forceinline__ f32x4 mfma16(s16x8 a, s16x8 b, f32x4 c) {
  return __builtin_amdgcn_mfma_f32_16x16x32_bf16(a, b, c, 0, 0, 0);
}

__device__ __forceinline__ void async16(const void* g, void* l) {
  __builtin_amdgcn_global_load_lds((const __attribute__((address_space(1))) void*)g,
                                   (__attribute__((address_space(3))) void*)l, 16, 0, 0);
}

__device__ __forceinline__ float exp2_fast(float x) {  // 2^x via v_exp_f32
  float r; asm("v_exp_f32 %0, %1" : "=v"(r) : "v"(x)); return r;
}

__device__ __forceinline__ unsigned cvt_pk_bf16(float lo, float hi) {
  unsigned r; asm("v_cvt_pk_bf16_f32 %0, %1, %2" : "=v"(r) : "v"(lo), "v"(hi)); return r;
}

// ---------------- x fp32 -> bf16 (pad rows zeroed) ----------------
__global__ void convert_x(const float* __restrict__ x, unsigned short* __restrict__ xb) {
  const long e = ((long)blockIdx.x * 256 + threadIdx.x) * 8;
  const long row = e / 768;
  s16x8 v;
  if (row < M_) {
#pragma unroll
    for (int j = 0; j < 8; ++j) v[j] = (short)f2bf(x[e + j]);
  } else {
    v = (s16x8){0,0,0,0,0,0,0,0};
  }
  *(s16x8*)&xb[e] = v;
}

// ---------------- W [R][C] fp32 -> W^T [C][R] bf16 ----------------
__global__ void transpose_convert(const float* __restrict__ in, unsigned short* __restrict__ out,
                                  int R, int Ccols) {
  __shared__ float tile[64][65];
  const int tc = blockIdx.x * 64, tr = blockIdx.y * 64;
#pragma unroll
  for (int i = 0; i < 16; ++i) {
    const int e = i * 256 + threadIdx.x;
    const int r = e >> 6, c = e & 63;
    tile[r][c] = in[(long)(tr + r) * Ccols + tc + c];
  }
  __syncthreads();
#pragma unroll
  for (int i = 0; i < 16; ++i) {
    const int e = i * 256 + threadIdx.x;
    const int c = e >> 6, r = e & 63;
    out[(long)(tc + c) * R + tr + r] = f2bf(tile[r][c]);
  }
}

// ---------------- zero the padding tokens 1009..1023 of K and V^T ----------------
__global__ void zero_pad(unsigned short* __restrict__ kb, unsigned short* __restrict__ vt) {
  const int t = blockIdx.x * 256 + threadIdx.x;
  if (t >= 368640) return;                       // 384*15*64 == 24576*15
  const int d = t & 63;
  const int r = t >> 6;                          // [0,5760)
  const int bh = r / 15, tok = 1009 + (r - bh * 15);
  kb[(((long)bh << 10) + tok) * 64 + d] = 0;     // K: [BH][1024][64]
  const int c = t % 15, row = t / 15;            // row < 24576
  vt[((long)row << 10) + 1009 + c] = 0;          // V^T: [BH*64 rows][1024]
}

// ---------------- GEMM: A[M x 768] bf16 row-major, Bt[N x 768] bf16 (B^T) ----------------
// MODE 0: qkv epilogue. q (PRE-SCALED by 0.125*log2e for exp2-domain softmax) and k
//   scattered row-major [BH][1024][64]; V-blocks (col0>=1536) transpose 128x128 through
//   LDS then write V^T [BH][64][1024] coalesced.
// MODE 1: fp32 out + bias.
template<int MODE>
__global__ __launch_bounds__(256, 2)
void gemm_bt(const unsigned short* __restrict__ A,
             const unsigned short* __restrict__ Bt,
             const float* __restrict__ bias,
             unsigned short* __restrict__ qo,
             unsigned short* __restrict__ ko,
             unsigned short* __restrict__ vo,
             float* __restrict__ fo) {
  __shared__ __align__(16) unsigned short smem[128 * 136];  // As(4096) | Bs(4096); V-transpose tile reuse
  unsigned short* const As = smem;
  unsigned short* const Bs = smem + 4096;
  const int tid = threadIdx.x;
  const int lane = tid & 63;
  const int wv = tid >> 6;
  const int bm = blockIdx.x % MT_;
  const int bn = blockIdx.x / MT_;
  const int row0 = bm * 128;
  const int col0 = bn * 128;
  const int wr = (wv >> 1) * 64;
  const int wc = (wv & 1) * 64;

  f32x4 acc[4][4] = {};
  for (int kt = 0; kt < 768; kt += 32) {
#pragma unroll
    for (int c = 0; c < 2; ++c) {
      const int lds_byte = c * 4096 + wv * 1024;   // wave-uniform LDS base
      const int elem = (lds_byte >> 1) + lane * 8; // per-lane element
      const int row = elem >> 5;
      const int kk = elem & 31;
      async16(A + (long)(row0 + row) * 768 + kt + kk, (char*)As + lds_byte);
      async16(Bt + (long)(col0 + row) * 768 + kt + kk, (char*)Bs + lds_byte);
    }
    __syncthreads();
    s16x8 af[4], bfr[4];
#pragma unroll
    for (int m = 0; m < 4; ++m)
      af[m] = *(const s16x8*)&As[(wr + m * 16 + (lane & 15)) * 32 + (lane >> 4) * 8];
#pragma unroll
    for (int n = 0; n < 4; ++n)
      bfr[n] = *(const s16x8*)&Bs[(wc + n * 16 + (lane & 15)) * 32 + (lane >> 4) * 8];
#pragma unroll
    for (int m = 0; m < 4; ++m)
#pragma unroll
      for (int n = 0; n < 4; ++n)
        acc[m][n] = mfma16(af[m], bfr[n], acc[m][n]);
    __syncthreads();
  }

  if (MODE == 0 && col0 >= 1536) {
    // ---- V path: stage transposed tile [d_local 0..127][tok 0..127] in LDS ----
#pragma unroll
    for (int m = 0; m < 4; ++m)
#pragma unroll
      for (int j = 0; j < 4; ++j)
#pragma unroll
        for (int n = 0; n < 4; ++n) {
          const int dl = wc + n * 16 + (lane & 15);
          const int tk = wr + m * 16 + (lane >> 4) * 4 + j;
          smem[dl * 136 + tk] = f2bf(acc[m][n][j] + bias[col0 + dl]);
        }
    __syncthreads();
    const int h0 = (col0 - 1536) >> 6;
    const int b0 = row0 / N_;
    const int split = (b0 + 1) * N_ - row0;   // block tokens [0,split) belong to batch b0
#pragma unroll
    for (int it = 0; it < 8; ++it) {
      const int g = it * 256 + tid;
      const int dl = g >> 4;
      const int t8 = (g & 15) * 8;
      const s16x8 vv = *(const s16x8*)&smem[dl * 136 + t8];   // 16B aligned
      const int hh = h0 + (dl >> 6), dd = dl & 63;
#pragma unroll
      for (int jj = 0; jj < 8; ++jj) {
        const int tkb = t8 + jj;
        const int grow = row0 + tkb;
        if (grow < M_) {
          const int bb = (tkb < split) ? b0 : b0 + 1;
          const int ntok = grow - bb * N_;
          vo[(((((long)bb * H_ + hh) << 6) + dd) << 10) + ntok] = (unsigned short)vv[jj];
        }
      }
    }
    return;
  }

#pragma unroll
  for (int m = 0; m < 4; ++m) {
#pragma unroll
    for (int j = 0; j < 4; ++j) {
      const int grow = row0 + wr + m * 16 + (lane >> 4) * 4 + j;
      if (grow < M_) {
        if (MODE == 0) {
          const int b = grow / N_;
          const int ntok = grow - b * N_;
#pragma unroll
          for (int n = 0; n < 4; ++n) {
            const int col = col0 + wc + n * 16 + (lane & 15);
            float val = acc[m][n][j] + bias[col];
            const int which = col >= 768;       // 0: q, 1: k (V handled above)
            if (!which) val *= 0.18033688011112042f;  // 0.125 * log2(e): exp2-domain scores
            const int rem = col - which * 768;
            const int h = rem >> 6, d = rem & 63;
            const long bh = (long)b * H_ + h;
            unsigned short* dst = which ? ko : qo;
            dst[((bh << 10) + ntok) * 64 + d] = f2bf(val);
          }
        } else {
#pragma unroll
          for (int n = 0; n < 4; ++n) {
            const int col = col0 + wc + n * 16 + (lane & 15);
            fo[(long)grow * 768 + col] = acc[m][n][j] + bias[col];
          }
        }
      }
    }
  }
}

// ---------------- prompt segment: out[n=0] = v[n=0] (V^T layout) ----------------
__global__ void misc_copy(const unsigned short* __restrict__ vt, unsigned short* __restrict__ og) {
  const int t = blockIdx.x * 256 + threadIdx.x;
  if (t >= B_ * H_ * D_) return;
  const int d = t & 63;
  const int bh = t >> 6;
  const int b = bh / H_, h = bh - b * H_;
  og[((long)b * N_) * 768 + h * 64 + d] = vt[(((long)bh << 6) + d) << 10];
}

// ---------------- flash attention: block = (b, h, 64-query tile), KVBLK=64 ----------------
// SWAPPED layout: QK^T computed as mfma(K,Q) -> S^T[key][q=lane&15]; PV as mfma(V^T,P)
// -> O^T[d][q=lane&15]. Softmax state (m,l) is one scalar per lane; reductions are
// in-lane over 16 regs + 2 shfl_xor(16,32). Q pre-scaled by 0.125*log2e -> exp2 domain.
// Ps: per-q-row 128B, 16B-chunk XOR swizzle (^q&7): b64 writes 2-way (free), b128 reads
// conflict-free (8-lane phases span all 8 chunk positions).
__global__ __launch_bounds__(256, 4)
void attn_kernel(const unsigned short* __restrict__ qg,
                 const unsigned short* __restrict__ kg,
                 const unsigned short* __restrict__ vtg,
                 unsigned short* __restrict__ og) {
  __shared__ __align__(16) unsigned short Ks[2][64 * 64];
  __shared__ __align__(16) unsigned short Vts[2][64 * 64];
  __shared__ __align__(16) unsigned short Ps[64 * 64];

  // XCD-chunked swizzle: all 16 tiles of a (b,h) stay on one XCD's L2 (grid 6144 % 8 == 0)
  const int bid = blockIdx.x;
  const int swz = (bid & 7) * 768 + (bid >> 3);
  const int tile = swz & 15;
  const int bh = swz >> 4;
  const int b = bh / H_;
  const int h = bh - b * H_;
  int qbase, qend, kstart, ktiles, kend;
  if (tile < 7) { qbase = 1 + 64 * tile;       qend = 433;  kstart = 1; ktiles = 7;  kend = 433; }
  else          { qbase = 433 + 64 * (tile-7); qend = 1009; kstart = 0; ktiles = 16; kend = 1009; }
  const long base  = (long)bh << 10;   // K/Q row base
  const long vbase = (long)bh << 6;    // V^T row base (d-major rows)
  const int tid = threadIdx.x, lane = tid & 63, wv = tid >> 6;
  const int q15 = lane & 15, q7 = lane & 7, g = lane >> 4;

  // Q fragments (wave wv owns q rows [wv*16, wv*16+16); this lane's q-row = wv*16+q15)
  s16x8 qa[2];
  {
    const unsigned short* qp = qg + (base + qbase + wv * 16 + q15) * 64;
    qa[0] = *(const s16x8*)(qp + g * 8);
    qa[1] = *(const s16x8*)(qp + 32 + g * 8);
  }
  asm volatile("s_waitcnt vmcnt(0)" ::: "memory");  // Q landed; vmem counter now clean

  f32x4 o[4] = {};             // O^T[d = f*16 + g*4 + j][q = lane&15]
  float mrow = -1e30f, lrow = 0.f;

  // stage one 64-key tile of K and V^T: linear LDS dest, swizzled global src (4 async16/thread)
  auto stage = [&](int bufsel, int kb0) {
#pragma unroll
    for (int it = 0; it < 2; ++it) {
      const int ldsoff = (it * 256 + wv * 64) * 16;      // wave-uniform dest base
      const int gr = it * 256 + wv * 64 + lane;          // this lane's 16B granule
      const int rl = gr >> 3;                            // LDS row (key for K, d for V^T)
      const int cs = (gr & 7) ^ (rl & 7);                // pre-swizzled source chunk
      async16(kg + ((base + kb0 + rl) << 6) + cs * 8, (char*)&Ks[bufsel][0] + ldsoff);
      async16(vtg + ((vbase + rl) << 10) + kb0 + cs * 8, (char*)&Vts[bufsel][0] + ldsoff);
    }
  };

  const int prow = wv * 16 + q15;

  stage(0, kstart);
  for (int kt = 0; kt < ktiles; ++kt) {
    const int buf = kt & 1;
    const int kbase0 = kstart + 64 * kt;
    if (kt + 1 < ktiles) {
      stage(buf ^ 1, kbase0 + 64);
      asm volatile("s_waitcnt vmcnt(4)" ::: "memory");   // current tile's 4 DMAs landed
    } else {
      asm volatile("s_waitcnt vmcnt(0)" ::: "memory");
    }
    __builtin_amdgcn_s_barrier();

    // S^T = K Q^T (swapped operands): C[row=key][col=q]; lane holds keys n*16+g*4+j
    f32x4 s4[4];
    __builtin_amdgcn_s_setprio(1);
#pragma unroll
    for (int n = 0; n < 4; ++n) {
      const int krow = n * 16 + q15;
      const int r7 = krow & 7;
      f32x4 a = {};
      a = mfma16(*(const s16x8*)&Ks[buf][krow * 64 + ((g ^ r7) << 3)],       qa[0], a);
      a = mfma16(*(const s16x8*)&Ks[buf][krow * 64 + (((4 + g) ^ r7) << 3)], qa[1], a);
      s4[n] = a;
    }
    __builtin_amdgcn_s_setprio(0);

    if (kbase0 + 64 > kend) {                 // uniform branch: only last tile of a region
#pragma unroll
      for (int n = 0; n < 4; ++n)
#pragma unroll
        for (int j = 0; j < 4; ++j)
          if (kbase0 + n * 16 + g * 4 + j >= kend) s4[n][j] = -1e30f;
    }

    // row max: in-lane over 16, then across the 4 lane-groups
    float rmax = fmaxf(
        fmaxf(fmaxf(fmaxf(s4[0][0], s4[0][1]), fmaxf(s4[0][2], s4[0][3])),
              fmaxf(fmaxf(s4[1][0], s4[1][1]), fmaxf(s4[1][2], s4[1][3]))),
        fmaxf(fmaxf(fmaxf(s4[2][0], s4[2][1]), fmaxf(s4[2][2], s4[2][3])),
              fmaxf(fmaxf(s4[3][0], s4[3][1]), fmaxf(s4[3][2], s4[3][3]))));
    rmax = fmaxf(rmax, __shfl_xor(rmax, 16));
    rmax = fmaxf(rmax, __shfl_xor(rmax, 32));

    const float mnew = fmaxf(mrow, rmax);
    const float corr = exp2_fast(mrow - mnew);
    mrow = mnew;
#pragma unroll
    for (int f = 0; f < 4; ++f)
#pragma unroll
      for (int j = 0; j < 4; ++j) o[f][j] *= corr;

    float psum = 0.f;
#pragma unroll
    for (int n = 0; n < 4; ++n) {
#pragma unroll
      for (int j = 0; j < 4; ++j) {
        s4[n][j] = exp2_fast(s4[n][j] - mnew);
        psum += s4[n][j];
      }
      uint2 pw;
      pw.x = cvt_pk_bf16(s4[n][0], s4[n][1]);
      pw.y = cvt_pk_bf16(s4[n][2], s4[n][3]);
      // keys n*16+g*4..+3 -> 16B chunk (n*2+(g>>1))^q7, 8B half (g&1)
      *(uint2*)((char*)Ps + prow * 128 + (((n * 2 + (g >> 1)) ^ q7) << 4) + (g & 1) * 8) = pw;
    }
    psum += __shfl_xor(psum, 16);
    psum += __shfl_xor(psum, 32);
    lrow = lrow * corr + psum;

    // O^T += V^T P^T : A = V^T rows (d-major), B = P (lane's own q row, keys kf*32+g*8..+7)
    s16x8 pa[2];
#pragma unroll
    for (int kf = 0; kf < 2; ++kf)
      pa[kf] = *(const s16x8*)((char*)Ps + prow * 128 + (((kf * 4 + g) ^ q7) << 4));
    __builtin_amdgcn_s_setprio(1);
#pragma unroll
    for (int f = 0; f < 4; ++f) {
      const int vrow = f * 16 + q15;
      const int v7 = vrow & 7;
#pragma unroll
      for (int kf = 0; kf < 2; ++kf) {
        const s16x8 vb = *(const s16x8*)&Vts[buf][vrow * 64 + (((kf * 4 + g) ^ v7) << 3)];
        o[f] = mfma16(vb, pa[kf], o[f]);
      }
    }
    __builtin_amdgcn_s_setprio(0);

    // drain our ds_reads before anyone overwrites this buffer next iteration
    asm volatile("s_waitcnt lgkmcnt(0)" ::: "memory");
    __builtin_amdgcn_s_barrier();
  }

  const int qrow = qbase + wv * 16 + q15;
  if (qrow < qend) {
    const float inv = 1.0f / lrow;
    unsigned short* op = og + ((long)b * N_ + qrow) * 768 + h * 64 + g * 4;
#pragma unroll
    for (int f = 0; f < 4; ++f) {
      uint2 ow;
      ow.x = cvt_pk_bf16(o[f][0] * inv, o[f][1] * inv);
      ow.y = cvt_pk_bf16(o[f][2] * inv, o[f][3] * inv);
      *(uint2*)(op + f * 16) = ow;     // 8B store, d = f*16 + g*4 .. +3
    }
  }
}

extern "C" void kernel_launch(void* const* d_in, const int* in_sizes, int n_in,
                              void* d_out, int out_size, void* d_ws, size_t ws_size,
                              hipStream_t stream) {
  const float* x      = (const float*)d_in[0];
  const float* W_qkv  = (const float*)d_in[1];
  const float* b_qkv  = (const float*)d_in[2];
  const float* W_proj = (const float*)d_in[3];
  const float* b_proj = (const float*)d_in[4];
  float* out = (float*)d_out;

  unsigned short* ws = (unsigned short*)d_ws;
  unsigned short* wqkvT  = ws;                                  // [2304][768] bf16
  unsigned short* wprojT = wqkvT + (long)2304 * 768;            // [768][768] bf16
  unsigned short* qb = wprojT + (long)768 * 768;                // [B][H][1024][64] bf16
  const long kvsz = (long)B_ * H_ * NKV_ * D_;
  unsigned short* kb = qb + kvsz;                               // [B][H][1024][64] bf16
  unsigned short* vb = kb + kvsz;                               // V^T: [B][H][64][1024] bf16
  unsigned short* xb = vb + kvsz;                               // [MPAD][768] bf16
  unsigned short* attnout = xb;  // aliased: xb dead after QKV GEMM (stream-ordered)

  zero_pad<<<1440, 256, 0, stream>>>(kb, vb);
  convert_x<<<12144, 256, 0, stream>>>(x, xb);
  transpose_convert<<<dim3(2304 / 64, 768 / 64), 256, 0, stream>>>(W_qkv, wqkvT, 768, 2304);
  transpose_convert<<<dim3(768 / 64, 768 / 64), 256, 0, stream>>>(W_proj, wprojT, 768, 768);
  gemm_bt<0><<<MT_ * 18, 256, 0, stream>>>(xb, wqkvT, b_qkv, qb, kb, vb, nullptr);
  misc_copy<<<96, 256, 0, stream>>>(vb, attnout);
  attn_kernel<<<B_ * H_ * 16, 256, 0, stream>>>(qb, kb, vb, attnout);
  gemm_bt<1><<<MT_ * 6, 256, 0, stream>>>(attnout, wprojT, b_proj, nullptr, nullptr, nullptr, out);
}

// Round 5
// 418.532 us; speedup vs baseline: 1.5673x; 1.0946x over previous
//
#include <hip/hip_runtime.h>

#define B_ 32
#define N_ 1009
#define C_ 768
#define H_ 12
#define D_ 64
#define M_ (B_*N_)          // 32288 tokens
#define MT_ 253             // ceil(M/128)
#define MPAD_ (MT_*128)     // 32384
#define NKV_ 1024           // padded sequence length for q/k/v storage

typedef __attribute__((ext_vector_type(4))) float f32x4;
typedef __attribute__((ext_vector_type(8))) short s16x8;

__device__ __forceinline__ unsigned short f2bf(float f) {
  union { float f; unsigned u; } x; x.f = f;
  unsigned r = x.u + 0x7fffu + ((x.u >> 16) & 1u);
  return (unsigned short)(r >> 16);
}

__device__ __forceinline__ f32x4 mfma16(s16x8 a, s16x8 b, f32x4 c) {
  return __builtin_amdgcn_mfma_f32_16x16x32_bf16(a, b, c, 0, 0, 0);
}

__device__ __forceinline__ void async16(const void* g, void* l) {
  __builtin_amdgcn_global_load_lds((const __attribute__((address_space(1))) void*)g,
                                   (__attribute__((address_space(3))) void*)l, 16, 0, 0);
}

__device__ __forceinline__ float exp2_fast(float x) {  // 2^x via v_exp_f32
  float r; asm("v_exp_f32 %0, %1" : "=v"(r) : "v"(x)); return r;
}

__device__ __forceinline__ unsigned cvt_pk_bf16(float lo, float hi) {
  unsigned r; asm("v_cvt_pk_bf16_f32 %0, %1, %2" : "=v"(r) : "v"(lo), "v"(hi)); return r;
}

// bijective XCD-chunk swizzle (m204): XCD x gets a contiguous range of work ids
template<int NWG>
__device__ __forceinline__ int xcd_swz(int bid) {
  constexpr int q = NWG >> 3, r = NWG & 7;
  const int x = bid & 7, l = bid >> 3;
  return (x < r ? x * (q + 1) : r * (q + 1) + (x - r) * q) + l;
}

// ---------------- x fp32 -> bf16 (pad rows zeroed) ----------------
__global__ void convert_x(const float* __restrict__ x, unsigned short* __restrict__ xb) {
  const long e = ((long)blockIdx.x * 256 + threadIdx.x) * 8;
  const long row = e / 768;
  s16x8 v;
  if (row < M_) {
#pragma unroll
    for (int j = 0; j < 8; ++j) v[j] = (short)f2bf(x[e + j]);
  } else {
    v = (s16x8){0,0,0,0,0,0,0,0};
  }
  *(s16x8*)&xb[e] = v;
}

// ---------------- W [R][C] fp32 -> W^T [C][R] bf16 ----------------
__global__ void transpose_convert(const float* __restrict__ in, unsigned short* __restrict__ out,
                                  int R, int Ccols) {
  __shared__ float tile[64][65];
  const int tc = blockIdx.x * 64, tr = blockIdx.y * 64;
#pragma unroll
  for (int i = 0; i < 16; ++i) {
    const int e = i * 256 + threadIdx.x;
    const int r = e >> 6, c = e & 63;
    tile[r][c] = in[(long)(tr + r) * Ccols + tc + c];
  }
  __syncthreads();
#pragma unroll
  for (int i = 0; i < 16; ++i) {
    const int e = i * 256 + threadIdx.x;
    const int c = e >> 6, r = e & 63;
    out[(long)(tc + c) * R + tr + r] = f2bf(tile[r][c]);
  }
}

// ---------------- zero the padding tokens 1009..1023 of K and V^T ----------------
__global__ void zero_pad(unsigned short* __restrict__ kb, unsigned short* __restrict__ vt) {
  const int t = blockIdx.x * 256 + threadIdx.x;
  if (t >= 368640) return;                       // 384*15*64 == 24576*15
  const int d = t & 63;
  const int r = t >> 6;                          // [0,5760)
  const int bh = r / 15, tok = 1009 + (r - bh * 15);
  kb[(((long)bh << 10) + tok) * 64 + d] = 0;     // K: [BH][1024][64]
  const int c = t % 15, row = t / 15;            // row < 24576
  vt[((long)row << 10) + 1009 + c] = 0;          // V^T: [BH*64 rows][1024]
}

// ---------------- GEMM: A[M x 768] bf16 row-major, Bt[N x 768] bf16 (B^T) ----------------
// Grid: A-reuse-major (bm = swz/NBN) + bijective XCD chunking -> each XCD's working set
//   = 1 A-tile (196KB) + full B panel (<=3.5MB), L2-resident. LDS tiles XOR-swizzled
//   (chunk ^= (row>>1)&3, pre-swizzled global src) -> 2-way-free ds_read_b128.
// MODE 0: qkv epilogue. q (PRE-SCALED by 0.125*log2e) / k row-major [BH][1024][64];
//   V-blocks (col0>=1536) transpose 128x128 through LDS then write V^T coalesced.
// MODE 1: fp32 out + bias.
template<int MODE>
__global__ __launch_bounds__(256, 2)
void gemm_bt(const unsigned short* __restrict__ A,
             const unsigned short* __restrict__ Bt,
             const float* __restrict__ bias,
             unsigned short* __restrict__ qo,
             unsigned short* __restrict__ ko,
             unsigned short* __restrict__ vo,
             float* __restrict__ fo) {
  __shared__ __align__(16) unsigned short smem[128 * 136];  // As(4096) | Bs(4096); V-transpose tile reuse
  unsigned short* const As = smem;
  unsigned short* const Bs = smem + 4096;
  const int tid = threadIdx.x;
  const int lane = tid & 63;
  const int wv = tid >> 6;
  constexpr int NBN = (MODE == 0) ? 18 : 6;
  const int swzid = xcd_swz<MT_ * NBN>(blockIdx.x);
  const int bm = swzid / NBN;
  const int bn = swzid - bm * NBN;
  const int row0 = bm * 128;
  const int col0 = bn * 128;
  const int wr = (wv >> 1) * 64;
  const int wc = (wv & 1) * 64;

  f32x4 acc[4][4] = {};
  for (int kt = 0; kt < 768; kt += 32) {
#pragma unroll
    for (int c = 0; c < 2; ++c) {
      const int lds_byte = c * 4096 + wv * 1024;   // wave-uniform LDS base
      const int gg = c * 256 + wv * 64 + lane;     // this lane's 16B granule
      const int row = gg >> 2;                     // tile row (4 granules/row)
      const int ck = ((gg & 3) ^ ((row >> 1) & 3)) << 3;  // pre-swizzled source chunk
      async16(A + (long)(row0 + row) * 768 + kt + ck, (char*)As + lds_byte);
      async16(Bt + (long)(col0 + row) * 768 + kt + ck, (char*)Bs + lds_byte);
    }
    __syncthreads();
    s16x8 af[4], bfr[4];
#pragma unroll
    for (int m = 0; m < 4; ++m) {
      const int rA = wr + m * 16 + (lane & 15);
      af[m] = *(const s16x8*)&As[rA * 32 + (((lane >> 4) ^ ((rA >> 1) & 3)) << 3)];
    }
#pragma unroll
    for (int n = 0; n < 4; ++n) {
      const int rB = wc + n * 16 + (lane & 15);
      bfr[n] = *(const s16x8*)&Bs[rB * 32 + (((lane >> 4) ^ ((rB >> 1) & 3)) << 3)];
    }
#pragma unroll
    for (int m = 0; m < 4; ++m)
#pragma unroll
      for (int n = 0; n < 4; ++n)
        acc[m][n] = mfma16(af[m], bfr[n], acc[m][n]);
    __syncthreads();
  }

  if (MODE == 0 && col0 >= 1536) {
    // ---- V path: stage transposed tile [d_local 0..127][tok 0..127] in LDS ----
#pragma unroll
    for (int m = 0; m < 4; ++m)
#pragma unroll
      for (int j = 0; j < 4; ++j)
#pragma unroll
        for (int n = 0; n < 4; ++n) {
          const int dl = wc + n * 16 + (lane & 15);
          const int tk = wr + m * 16 + (lane >> 4) * 4 + j;
          smem[dl * 136 + tk] = f2bf(acc[m][n][j] + bias[col0 + dl]);
        }
    __syncthreads();
    const int h0 = (col0 - 1536) >> 6;
    const int b0 = row0 / N_;
    const int split = (b0 + 1) * N_ - row0;   // block tokens [0,split) belong to batch b0
#pragma unroll
    for (int it = 0; it < 8; ++it) {
      const int g = it * 256 + tid;
      const int dl = g >> 4;
      const int t8 = (g & 15) * 8;
      const s16x8 vv = *(const s16x8*)&smem[dl * 136 + t8];   // 16B aligned
      const int hh = h0 + (dl >> 6), dd = dl & 63;
#pragma unroll
      for (int jj = 0; jj < 8; ++jj) {
        const int tkb = t8 + jj;
        const int grow = row0 + tkb;
        if (grow < M_) {
          const int bb = (tkb < split) ? b0 : b0 + 1;
          const int ntok = grow - bb * N_;
          vo[(((((long)bb * H_ + hh) << 6) + dd) << 10) + ntok] = (unsigned short)vv[jj];
        }
      }
    }
    return;
  }

#pragma unroll
  for (int m = 0; m < 4; ++m) {
#pragma unroll
    for (int j = 0; j < 4; ++j) {
      const int grow = row0 + wr + m * 16 + (lane >> 4) * 4 + j;
      if (grow < M_) {
        if (MODE == 0) {
          const int b = grow / N_;
          const int ntok = grow - b * N_;
#pragma unroll
          for (int n = 0; n < 4; ++n) {
            const int col = col0 + wc + n * 16 + (lane & 15);
            float val = acc[m][n][j] + bias[col];
            const int which = col >= 768;       // 0: q, 1: k (V handled above)
            if (!which) val *= 0.18033688011112042f;  // 0.125 * log2(e): exp2-domain scores
            const int rem = col - which * 768;
            const int h = rem >> 6, d = rem & 63;
            const long bh = (long)b * H_ + h;
            unsigned short* dst = which ? ko : qo;
            dst[((bh << 10) + ntok) * 64 + d] = f2bf(val);
          }
        } else {
#pragma unroll
          for (int n = 0; n < 4; ++n) {
            const int col = col0 + wc + n * 16 + (lane & 15);
            fo[(long)grow * 768 + col] = acc[m][n][j] + bias[col];
          }
        }
      }
    }
  }
}

// ---------------- prompt segment: out[n=0] = v[n=0] (V^T layout) ----------------
__global__ void misc_copy(const unsigned short* __restrict__ vt, unsigned short* __restrict__ og) {
  const int t = blockIdx.x * 256 + threadIdx.x;
  if (t >= B_ * H_ * D_) return;
  const int d = t & 63;
  const int bh = t >> 6;
  const int b = bh / H_, h = bh - b * H_;
  og[((long)b * N_) * 768 + h * 64 + d] = vt[(((long)bh << 6) + d) << 10];
}

// ---------------- flash attention: block = (b, h, 64-query tile), KVBLK=64 ----------------
// SWAPPED layout: QK^T computed as mfma(K,Q) -> S^T[key][q=lane&15]; PV as mfma(V^T,P)
// -> O^T[d][q=lane&15]. Softmax state (m,l) is one scalar per lane; reductions are
// in-lane over 16 regs + 2 shfl_xor(16,32). Q pre-scaled by 0.125*log2e -> exp2 domain.
__global__ __launch_bounds__(256, 4)
void attn_kernel(const unsigned short* __restrict__ qg,
                 const unsigned short* __restrict__ kg,
                 const unsigned short* __restrict__ vtg,
                 unsigned short* __restrict__ og) {
  __shared__ __align__(16) unsigned short Ks[2][64 * 64];
  __shared__ __align__(16) unsigned short Vts[2][64 * 64];
  __shared__ __align__(16) unsigned short Ps[64 * 64];

  // XCD-chunked swizzle: all 16 tiles of a (b,h) stay on one XCD's L2 (grid 6144 % 8 == 0)
  const int bid = blockIdx.x;
  const int swz = (bid & 7) * 768 + (bid >> 3);
  const int tile = swz & 15;
  const int bh = swz >> 4;
  const int b = bh / H_;
  const int h = bh - b * H_;
  int qbase, qend, kstart, ktiles, kend;
  if (tile < 7) { qbase = 1 + 64 * tile;       qend = 433;  kstart = 1; ktiles = 7;  kend = 433; }
  else          { qbase = 433 + 64 * (tile-7); qend = 1009; kstart = 0; ktiles = 16; kend = 1009; }
  const long base  = (long)bh << 10;   // K/Q row base
  const long vbase = (long)bh << 6;    // V^T row base (d-major rows)
  const int tid = threadIdx.x, lane = tid & 63, wv = tid >> 6;
  const int q15 = lane & 15, q7 = lane & 7, g = lane >> 4;

  // Q fragments (wave wv owns q rows [wv*16, wv*16+16); this lane's q-row = wv*16+q15)
  s16x8 qa[2];
  {
    const unsigned short* qp = qg + (base + qbase + wv * 16 + q15) * 64;
    qa[0] = *(const s16x8*)(qp + g * 8);
    qa[1] = *(const s16x8*)(qp + 32 + g * 8);
  }
  asm volatile("s_waitcnt vmcnt(0)" ::: "memory");  // Q landed; vmem counter now clean

  f32x4 o[4] = {};             // O^T[d = f*16 + g*4 + j][q = lane&15]
  float mrow = -1e30f, lrow = 0.f;

  // stage one 64-key tile of K and V^T: linear LDS dest, swizzled global src (4 async16/thread)
  auto stage = [&](int bufsel, int kb0) {
#pragma unroll
    for (int it = 0; it < 2; ++it) {
      const int ldsoff = (it * 256 + wv * 64) * 16;      // wave-uniform dest base
      const int gr = it * 256 + wv * 64 + lane;          // this lane's 16B granule
      const int rl = gr >> 3;                            // LDS row (key for K, d for V^T)
      const int cs = (gr & 7) ^ (rl & 7);                // pre-swizzled source chunk
      async16(kg + ((base + kb0 + rl) << 6) + cs * 8, (char*)&Ks[bufsel][0] + ldsoff);
      async16(vtg + ((vbase + rl) << 10) + kb0 + cs * 8, (char*)&Vts[bufsel][0] + ldsoff);
    }
  };

  const int prow = wv * 16 + q15;

  stage(0, kstart);
  for (int kt = 0; kt < ktiles; ++kt) {
    const int buf = kt & 1;
    const int kbase0 = kstart + 64 * kt;
    if (kt + 1 < ktiles) {
      stage(buf ^ 1, kbase0 + 64);
      asm volatile("s_waitcnt vmcnt(4)" ::: "memory");   // current tile's 4 DMAs landed
    } else {
      asm volatile("s_waitcnt vmcnt(0)" ::: "memory");
    }
    __builtin_amdgcn_s_barrier();

    // S^T = K Q^T (swapped operands): C[row=key][col=q]; lane holds keys n*16+g*4+j
    f32x4 s4[4];
    __builtin_amdgcn_s_setprio(1);
#pragma unroll
    for (int n = 0; n < 4; ++n) {
      const int krow = n * 16 + q15;
      const int r7 = krow & 7;
      f32x4 a = {};
      a = mfma16(*(const s16x8*)&Ks[buf][krow * 64 + ((g ^ r7) << 3)],       qa[0], a);
      a = mfma16(*(const s16x8*)&Ks[buf][krow * 64 + (((4 + g) ^ r7) << 3)], qa[1], a);
      s4[n] = a;
    }
    __builtin_amdgcn_s_setprio(0);

    if (kbase0 + 64 > kend) {                 // uniform branch: only last tile of a region
#pragma unroll
      for (int n = 0; n < 4; ++n)
#pragma unroll
        for (int j = 0; j < 4; ++j)
          if (kbase0 + n * 16 + g * 4 + j >= kend) s4[n][j] = -1e30f;
    }

    // row max: in-lane over 16, then across the 4 lane-groups
    float rmax = fmaxf(
        fmaxf(fmaxf(fmaxf(s4[0][0], s4[0][1]), fmaxf(s4[0][2], s4[0][3])),
              fmaxf(fmaxf(s4[1][0], s4[1][1]), fmaxf(s4[1][2], s4[1][3]))),
        fmaxf(fmaxf(fmaxf(s4[2][0], s4[2][1]), fmaxf(s4[2][2], s4[2][3])),
              fmaxf(fmaxf(s4[3][0], s4[3][1]), fmaxf(s4[3][2], s4[3][3]))));
    rmax = fmaxf(rmax, __shfl_xor(rmax, 16));
    rmax = fmaxf(rmax, __shfl_xor(rmax, 32));

    const float mnew = fmaxf(mrow, rmax);
    const float corr = exp2_fast(mrow - mnew);
    mrow = mnew;
#pragma unroll
    for (int f = 0; f < 4; ++f)
#pragma unroll
      for (int j = 0; j < 4; ++j) o[f][j] *= corr;

    float psum = 0.f;
#pragma unroll
    for (int n = 0; n < 4; ++n) {
#pragma unroll
      for (int j = 0; j < 4; ++j) {
        s4[n][j] = exp2_fast(s4[n][j] - mnew);
        psum += s4[n][j];
      }
      uint2 pw;
      pw.x = cvt_pk_bf16(s4[n][0], s4[n][1]);
      pw.y = cvt_pk_bf16(s4[n][2], s4[n][3]);
      // keys n*16+g*4..+3 -> 16B chunk (n*2+(g>>1))^q7, 8B half (g&1)
      *(uint2*)((char*)Ps + prow * 128 + (((n * 2 + (g >> 1)) ^ q7) << 4) + (g & 1) * 8) = pw;
    }
    psum += __shfl_xor(psum, 16);
    psum += __shfl_xor(psum, 32);
    lrow = lrow * corr + psum;

    // O^T += V^T P^T : A = V^T rows (d-major), B = P (lane's own q row, keys kf*32+g*8..+7)
    s16x8 pa[2];
#pragma unroll
    for (int kf = 0; kf < 2; ++kf)
      pa[kf] = *(const s16x8*)((char*)Ps + prow * 128 + (((kf * 4 + g) ^ q7) << 4));
    __builtin_amdgcn_s_setprio(1);
#pragma unroll
    for (int f = 0; f < 4; ++f) {
      const int vrow = f * 16 + q15;
      const int v7 = vrow & 7;
#pragma unroll
      for (int kf = 0; kf < 2; ++kf) {
        const s16x8 vb = *(const s16x8*)&Vts[buf][vrow * 64 + (((kf * 4 + g) ^ v7) << 3)];
        o[f] = mfma16(vb, pa[kf], o[f]);
      }
    }
    __builtin_amdgcn_s_setprio(0);

    // drain our ds_reads before anyone overwrites this buffer next iteration
    asm volatile("s_waitcnt lgkmcnt(0)" ::: "memory");
    __builtin_amdgcn_s_barrier();
  }

  const int qrow = qbase + wv * 16 + q15;
  if (qrow < qend) {
    const float inv = 1.0f / lrow;
    unsigned short* op = og + ((long)b * N_ + qrow) * 768 + h * 64 + g * 4;
#pragma unroll
    for (int f = 0; f < 4; ++f) {
      uint2 ow;
      ow.x = cvt_pk_bf16(o[f][0] * inv, o[f][1] * inv);
      ow.y = cvt_pk_bf16(o[f][2] * inv, o[f][3] * inv);
      *(uint2*)(op + f * 16) = ow;     // 8B store, d = f*16 + g*4 .. +3
    }
  }
}

extern "C" void kernel_launch(void* const* d_in, const int* in_sizes, int n_in,
                              void* d_out, int out_size, void* d_ws, size_t ws_size,
                              hipStream_t stream) {
  const float* x      = (const float*)d_in[0];
  const float* W_qkv  = (const float*)d_in[1];
  const float* b_qkv  = (const float*)d_in[2];
  const float* W_proj = (const float*)d_in[3];
  const float* b_proj = (const float*)d_in[4];
  float* out = (float*)d_out;

  unsigned short* ws = (unsigned short*)d_ws;
  unsigned short* wqkvT  = ws;                                  // [2304][768] bf16
  unsigned short* wprojT = wqkvT + (long)2304 * 768;            // [768][768] bf16
  unsigned short* qb = wprojT + (long)768 * 768;                // [B][H][1024][64] bf16
  const long kvsz = (long)B_ * H_ * NKV_ * D_;
  unsigned short* kb = qb + kvsz;                               // [B][H][1024][64] bf16
  unsigned short* vb = kb + kvsz;                               // V^T: [B][H][64][1024] bf16
  unsigned short* xb = vb + kvsz;                               // [MPAD][768] bf16
  unsigned short* attnout = xb;  // aliased: xb dead after QKV GEMM (stream-ordered)

  zero_pad<<<1440, 256, 0, stream>>>(kb, vb);
  convert_x<<<12144, 256, 0, stream>>>(x, xb);
  transpose_convert<<<dim3(2304 / 64, 768 / 64), 256, 0, stream>>>(W_qkv, wqkvT, 768, 2304);
  transpose_convert<<<dim3(768 / 64, 768 / 64), 256, 0, stream>>>(W_proj, wprojT, 768, 768);
  gemm_bt<0><<<MT_ * 18, 256, 0, stream>>>(xb, wqkvT, b_qkv, qb, kb, vb, nullptr);
  misc_copy<<<96, 256, 0, stream>>>(vb, attnout);
  attn_kernel<<<B_ * H_ * 16, 256, 0, stream>>>(qb, kb, vb, attnout);
  gemm_bt<1><<<MT_ * 6, 256, 0, stream>>>(attnout, wprojT, b_proj, nullptr, nullptr, nullptr, out);
}

// Round 6
// 413.933 us; speedup vs baseline: 1.5847x; 1.0111x over previous
//
#include <hip/hip_runtime.h>

#define B_ 32
#define N_ 1009
#define C_ 768
#define H_ 12
#define D_ 64
#define M_ (B_*N_)          // 32288 tokens
#define MT_ 253             // ceil(M/128)
#define MPAD_ (MT_*128)     // 32384
#define NKV_ 1024           // padded sequence length for q/k/v storage

typedef __attribute__((ext_vector_type(4))) float f32x4;
typedef __attribute__((ext_vector_type(8))) short s16x8;

__device__ __forceinline__ unsigned short f2bf(float f) {
  union { float f; unsigned u; } x; x.f = f;
  unsigned r = x.u + 0x7fffu + ((x.u >> 16) & 1u);
  return (unsigned short)(r >> 16);
}

__device__ __forceinline__ f32x4 mfma16(s16x8 a, s16x8 b, f32x4 c) {
  return __builtin_amdgcn_mfma_f32_16x16x32_bf16(a, b, c, 0, 0, 0);
}

__device__ __forceinline__ void async16(const void* g, void* l) {
  __builtin_amdgcn_global_load_lds((const __attribute__((address_space(1))) void*)g,
                                   (__attribute__((address_space(3))) void*)l, 16, 0, 0);
}

__device__ __forceinline__ float exp2_fast(float x) {  // 2^x via v_exp_f32
  float r; asm("v_exp_f32 %0, %1" : "=v"(r) : "v"(x)); return r;
}

__device__ __forceinline__ unsigned cvt_pk_bf16(float lo, float hi) {
  unsigned r; asm("v_cvt_pk_bf16_f32 %0, %1, %2" : "=v"(r) : "v"(lo), "v"(hi)); return r;
}

// bijective XCD-chunk swizzle (m204): XCD x gets a contiguous range of work ids
template<int NWG>
__device__ __forceinline__ int xcd_swz(int bid) {
  constexpr int q = NWG >> 3, r = NWG & 7;
  const int x = bid & 7, l = bid >> 3;
  return (x < r ? x * (q + 1) : r * (q + 1) + (x - r) * q) + l;
}

// ---------------- x fp32 -> bf16 (pad rows zeroed) ----------------
__global__ void convert_x(const float* __restrict__ x, unsigned short* __restrict__ xb) {
  const long e = ((long)blockIdx.x * 256 + threadIdx.x) * 8;
  const long row = e / 768;
  s16x8 v;
  if (row < M_) {
#pragma unroll
    for (int j = 0; j < 8; ++j) v[j] = (short)f2bf(x[e + j]);
  } else {
    v = (s16x8){0,0,0,0,0,0,0,0};
  }
  *(s16x8*)&xb[e] = v;
}

// ---------------- W [R][C] fp32 -> W^T [C][R] bf16 ----------------
__global__ void transpose_convert(const float* __restrict__ in, unsigned short* __restrict__ out,
                                  int R, int Ccols) {
  __shared__ float tile[64][65];
  const int tc = blockIdx.x * 64, tr = blockIdx.y * 64;
#pragma unroll
  for (int i = 0; i < 16; ++i) {
    const int e = i * 256 + threadIdx.x;
    const int r = e >> 6, c = e & 63;
    tile[r][c] = in[(long)(tr + r) * Ccols + tc + c];
  }
  __syncthreads();
#pragma unroll
  for (int i = 0; i < 16; ++i) {
    const int e = i * 256 + threadIdx.x;
    const int c = e >> 6, r = e & 63;
    out[(long)(tc + c) * R + tr + r] = f2bf(tile[r][c]);
  }
}

// ---------------- zero the padding tokens 1009..1023 of K and V^T ----------------
__global__ void zero_pad(unsigned short* __restrict__ kb, unsigned short* __restrict__ vt) {
  const int t = blockIdx.x * 256 + threadIdx.x;
  if (t >= 368640) return;                       // 384*15*64 == 24576*15
  const int d = t & 63;
  const int r = t >> 6;                          // [0,5760)
  const int bh = r / 15, tok = 1009 + (r - bh * 15);
  kb[(((long)bh << 10) + tok) * 64 + d] = 0;     // K: [BH][1024][64]
  const int c = t % 15, row = t / 15;            // row < 24576
  vt[((long)row << 10) + 1009 + c] = 0;          // V^T: [BH*64 rows][1024]
}

// ---------------- GEMM: A[M x 768] bf16 row-major, Bt[N x 768] bf16 (B^T) ----------------
// Grid: A-reuse-major (bm = swz/NBN) + bijective XCD chunking -> XCD working set L2-fits.
// K-loop: DOUBLE-BUFFERED LDS + counted vmcnt(4) + raw barriers (2-phase pipeline, same
//   discipline as attn_kernel) -- prefetch of tile t+1 stays in flight across compute of t.
// LDS tiles XOR-swizzled (chunk ^= (row>>1)&3, pre-swizzled global src) -> 2-way-free reads.
// MODE 0: qkv epilogue. q (PRE-SCALED by 0.125*log2e) / k row-major [BH][1024][64];
//   V-blocks (col0>=1536) transpose 128x128 through LDS then write V^T coalesced.
// MODE 1: fp32 out + bias.
template<int MODE>
__global__ __launch_bounds__(256, 4)
void gemm_bt(const unsigned short* __restrict__ A,
             const unsigned short* __restrict__ Bt,
             const float* __restrict__ bias,
             unsigned short* __restrict__ qo,
             unsigned short* __restrict__ ko,
             unsigned short* __restrict__ vo,
             float* __restrict__ fo) {
  // layout (bytes): As[0] @0, As[1] @8192, Bs[0] @16384, Bs[1] @24576; epilogue tile reuses all
  __shared__ __align__(16) unsigned short smem[17408];   // 34816 B -> 4 blocks/CU
  const int tid = threadIdx.x;
  const int lane = tid & 63;
  const int wv = tid >> 6;
  constexpr int NBN = (MODE == 0) ? 18 : 6;
  const int swzid = xcd_swz<MT_ * NBN>(blockIdx.x);
  const int bm = swzid / NBN;
  const int bn = swzid - bm * NBN;
  const int row0 = bm * 128;
  const int col0 = bn * 128;
  const int wr = (wv >> 1) * 64;
  const int wc = (wv & 1) * 64;

  // stage one 128x32 K-step of A and B into buffer bufsel (4 async16/thread)
  auto stage = [&](int bufsel, int kt) {
#pragma unroll
    for (int c = 0; c < 2; ++c) {
      const int lds_off = c * 4096 + wv * 1024;    // wave-uniform byte base within tile
      const int gg = c * 256 + wv * 64 + lane;     // this lane's 16B granule
      const int row = gg >> 2;                     // tile row (4 granules/row)
      const int ck = ((gg & 3) ^ ((row >> 1) & 3)) << 3;  // pre-swizzled source chunk
      async16(A + (long)(row0 + row) * 768 + kt + ck, (char*)smem + bufsel * 8192 + lds_off);
      async16(Bt + (long)(col0 + row) * 768 + kt + ck, (char*)smem + 16384 + bufsel * 8192 + lds_off);
    }
  };

  f32x4 acc[4][4] = {};
  stage(0, 0);
  for (int it = 0; it < 24; ++it) {
    const int buf = it & 1;
    if (it + 1 < 24) {
      stage(buf ^ 1, (it + 1) * 32);
      asm volatile("s_waitcnt vmcnt(4)" ::: "memory");   // current tile's 4 DMAs landed
    } else {
      asm volatile("s_waitcnt vmcnt(0)" ::: "memory");
    }
    __builtin_amdgcn_s_barrier();

    const unsigned short* Asb = smem + buf * 4096;          // shorts
    const unsigned short* Bsb = smem + 8192 + buf * 4096;
    s16x8 af[4], bfr[4];
#pragma unroll
    for (int m = 0; m < 4; ++m) {
      const int rA = wr + m * 16 + (lane & 15);
      af[m] = *(const s16x8*)&Asb[rA * 32 + (((lane >> 4) ^ ((rA >> 1) & 3)) << 3)];
    }
#pragma unroll
    for (int n = 0; n < 4; ++n) {
      const int rB = wc + n * 16 + (lane & 15);
      bfr[n] = *(const s16x8*)&Bsb[rB * 32 + (((lane >> 4) ^ ((rB >> 1) & 3)) << 3)];
    }
    __builtin_amdgcn_s_setprio(1);
#pragma unroll
    for (int m = 0; m < 4; ++m)
#pragma unroll
      for (int n = 0; n < 4; ++n)
        acc[m][n] = mfma16(af[m], bfr[n], acc[m][n]);
    __builtin_amdgcn_s_setprio(0);

    // drain our ds_reads before anyone overwrites this buffer next iteration
    asm volatile("s_waitcnt lgkmcnt(0)" ::: "memory");
    __builtin_amdgcn_s_barrier();
  }

  if (MODE == 0 && col0 >= 1536) {
    // ---- V path: stage transposed tile [d_local 0..127][tok 0..127] in LDS ----
#pragma unroll
    for (int m = 0; m < 4; ++m)
#pragma unroll
      for (int j = 0; j < 4; ++j)
#pragma unroll
        for (int n = 0; n < 4; ++n) {
          const int dl = wc + n * 16 + (lane & 15);
          const int tk = wr + m * 16 + (lane >> 4) * 4 + j;
          smem[dl * 136 + tk] = f2bf(acc[m][n][j] + bias[col0 + dl]);
        }
    __syncthreads();
    const int h0 = (col0 - 1536) >> 6;
    const int b0 = row0 / N_;
    const int split = (b0 + 1) * N_ - row0;   // block tokens [0,split) belong to batch b0
#pragma unroll
    for (int it = 0; it < 8; ++it) {
      const int g = it * 256 + tid;
      const int dl = g >> 4;
      const int t8 = (g & 15) * 8;
      const s16x8 vv = *(const s16x8*)&smem[dl * 136 + t8];   // 16B aligned
      const int hh = h0 + (dl >> 6), dd = dl & 63;
#pragma unroll
      for (int jj = 0; jj < 8; ++jj) {
        const int tkb = t8 + jj;
        const int grow = row0 + tkb;
        if (grow < M_) {
          const int bb = (tkb < split) ? b0 : b0 + 1;
          const int ntok = grow - bb * N_;
          vo[(((((long)bb * H_ + hh) << 6) + dd) << 10) + ntok] = (unsigned short)vv[jj];
        }
      }
    }
    return;
  }

#pragma unroll
  for (int m = 0; m < 4; ++m) {
#pragma unroll
    for (int j = 0; j < 4; ++j) {
      const int grow = row0 + wr + m * 16 + (lane >> 4) * 4 + j;
      if (grow < M_) {
        if (MODE == 0) {
          const int b = grow / N_;
          const int ntok = grow - b * N_;
#pragma unroll
          for (int n = 0; n < 4; ++n) {
            const int col = col0 + wc + n * 16 + (lane & 15);
            float val = acc[m][n][j] + bias[col];
            const int which = col >= 768;       // 0: q, 1: k (V handled above)
            if (!which) val *= 0.18033688011112042f;  // 0.125 * log2(e): exp2-domain scores
            const int rem = col - which * 768;
            const int h = rem >> 6, d = rem & 63;
            const long bh = (long)b * H_ + h;
            unsigned short* dst = which ? ko : qo;
            dst[((bh << 10) + ntok) * 64 + d] = f2bf(val);
          }
        } else {
#pragma unroll
          for (int n = 0; n < 4; ++n) {
            const int col = col0 + wc + n * 16 + (lane & 15);
            fo[(long)grow * 768 + col] = acc[m][n][j] + bias[col];
          }
        }
      }
    }
  }
}

// ---------------- prompt segment: out[n=0] = v[n=0] (V^T layout) ----------------
__global__ void misc_copy(const unsigned short* __restrict__ vt, unsigned short* __restrict__ og) {
  const int t = blockIdx.x * 256 + threadIdx.x;
  if (t >= B_ * H_ * D_) return;
  const int d = t & 63;
  const int bh = t >> 6;
  const int b = bh / H_, h = bh - b * H_;
  og[((long)b * N_) * 768 + h * 64 + d] = vt[(((long)bh << 6) + d) << 10];
}

// ---------------- flash attention: block = (b, h, 64-query tile), KVBLK=64 ----------------
// SWAPPED layout: QK^T computed as mfma(K,Q) -> S^T[key][q=lane&15]; PV as mfma(V^T,P)
// -> O^T[d][q=lane&15]. Softmax state (m,l) is one scalar per lane; reductions are
// in-lane over 16 regs + 2 shfl_xor(16,32). Q pre-scaled by 0.125*log2e -> exp2 domain.
__global__ __launch_bounds__(256, 4)
void attn_kernel(const unsigned short* __restrict__ qg,
                 const unsigned short* __restrict__ kg,
                 const unsigned short* __restrict__ vtg,
                 unsigned short* __restrict__ og) {
  __shared__ __align__(16) unsigned short Ks[2][64 * 64];
  __shared__ __align__(16) unsigned short Vts[2][64 * 64];
  __shared__ __align__(16) unsigned short Ps[64 * 64];

  // XCD-chunked swizzle: all 16 tiles of a (b,h) stay on one XCD's L2 (grid 6144 % 8 == 0)
  const int bid = blockIdx.x;
  const int swz = (bid & 7) * 768 + (bid >> 3);
  const int tile = swz & 15;
  const int bh = swz >> 4;
  const int b = bh / H_;
  const int h = bh - b * H_;
  int qbase, qend, kstart, ktiles, kend;
  if (tile < 7) { qbase = 1 + 64 * tile;       qend = 433;  kstart = 1; ktiles = 7;  kend = 433; }
  else          { qbase = 433 + 64 * (tile-7); qend = 1009; kstart = 0; ktiles = 16; kend = 1009; }
  const long base  = (long)bh << 10;   // K/Q row base
  const long vbase = (long)bh << 6;    // V^T row base (d-major rows)
  const int tid = threadIdx.x, lane = tid & 63, wv = tid >> 6;
  const int q15 = lane & 15, q7 = lane & 7, g = lane >> 4;

  // Q fragments (wave wv owns q rows [wv*16, wv*16+16); this lane's q-row = wv*16+q15)
  s16x8 qa[2];
  {
    const unsigned short* qp = qg + (base + qbase + wv * 16 + q15) * 64;
    qa[0] = *(const s16x8*)(qp + g * 8);
    qa[1] = *(const s16x8*)(qp + 32 + g * 8);
  }
  asm volatile("s_waitcnt vmcnt(0)" ::: "memory");  // Q landed; vmem counter now clean

  f32x4 o[4] = {};             // O^T[d = f*16 + g*4 + j][q = lane&15]
  float mrow = -1e30f, lrow = 0.f;

  // stage one 64-key tile of K and V^T: linear LDS dest, swizzled global src (4 async16/thread)
  auto stage = [&](int bufsel, int kb0) {
#pragma unroll
    for (int it = 0; it < 2; ++it) {
      const int ldsoff = (it * 256 + wv * 64) * 16;      // wave-uniform dest base
      const int gr = it * 256 + wv * 64 + lane;          // this lane's 16B granule
      const int rl = gr >> 3;                            // LDS row (key for K, d for V^T)
      const int cs = (gr & 7) ^ (rl & 7);                // pre-swizzled source chunk
      async16(kg + ((base + kb0 + rl) << 6) + cs * 8, (char*)&Ks[bufsel][0] + ldsoff);
      async16(vtg + ((vbase + rl) << 10) + kb0 + cs * 8, (char*)&Vts[bufsel][0] + ldsoff);
    }
  };

  const int prow = wv * 16 + q15;

  stage(0, kstart);
  for (int kt = 0; kt < ktiles; ++kt) {
    const int buf = kt & 1;
    const int kbase0 = kstart + 64 * kt;
    if (kt + 1 < ktiles) {
      stage(buf ^ 1, kbase0 + 64);
      asm volatile("s_waitcnt vmcnt(4)" ::: "memory");   // current tile's 4 DMAs landed
    } else {
      asm volatile("s_waitcnt vmcnt(0)" ::: "memory");
    }
    __builtin_amdgcn_s_barrier();

    // S^T = K Q^T (swapped operands): C[row=key][col=q]; lane holds keys n*16+g*4+j
    f32x4 s4[4];
    __builtin_amdgcn_s_setprio(1);
#pragma unroll
    for (int n = 0; n < 4; ++n) {
      const int krow = n * 16 + q15;
      const int r7 = krow & 7;
      f32x4 a = {};
      a = mfma16(*(const s16x8*)&Ks[buf][krow * 64 + ((g ^ r7) << 3)],       qa[0], a);
      a = mfma16(*(const s16x8*)&Ks[buf][krow * 64 + (((4 + g) ^ r7) << 3)], qa[1], a);
      s4[n] = a;
    }
    __builtin_amdgcn_s_setprio(0);

    if (kbase0 + 64 > kend) {                 // uniform branch: only last tile of a region
#pragma unroll
      for (int n = 0; n < 4; ++n)
#pragma unroll
        for (int j = 0; j < 4; ++j)
          if (kbase0 + n * 16 + g * 4 + j >= kend) s4[n][j] = -1e30f;
    }

    // row max: in-lane over 16, then across the 4 lane-groups
    float rmax = fmaxf(
        fmaxf(fmaxf(fmaxf(s4[0][0], s4[0][1]), fmaxf(s4[0][2], s4[0][3])),
              fmaxf(fmaxf(s4[1][0], s4[1][1]), fmaxf(s4[1][2], s4[1][3]))),
        fmaxf(fmaxf(fmaxf(s4[2][0], s4[2][1]), fmaxf(s4[2][2], s4[2][3])),
              fmaxf(fmaxf(s4[3][0], s4[3][1]), fmaxf(s4[3][2], s4[3][3]))));
    rmax = fmaxf(rmax, __shfl_xor(rmax, 16));
    rmax = fmaxf(rmax, __shfl_xor(rmax, 32));

    const float mnew = fmaxf(mrow, rmax);
    const float corr = exp2_fast(mrow - mnew);
    mrow = mnew;
#pragma unroll
    for (int f = 0; f < 4; ++f)
#pragma unroll
      for (int j = 0; j < 4; ++j) o[f][j] *= corr;

    float psum = 0.f;
#pragma unroll
    for (int n = 0; n < 4; ++n) {
#pragma unroll
      for (int j = 0; j < 4; ++j) {
        s4[n][j] = exp2_fast(s4[n][j] - mnew);
        psum += s4[n][j];
      }
      uint2 pw;
      pw.x = cvt_pk_bf16(s4[n][0], s4[n][1]);
      pw.y = cvt_pk_bf16(s4[n][2], s4[n][3]);
      // keys n*16+g*4..+3 -> 16B chunk (n*2+(g>>1))^q7, 8B half (g&1)
      *(uint2*)((char*)Ps + prow * 128 + (((n * 2 + (g >> 1)) ^ q7) << 4) + (g & 1) * 8) = pw;
    }
    psum += __shfl_xor(psum, 16);
    psum += __shfl_xor(psum, 32);
    lrow = lrow * corr + psum;

    // O^T += V^T P^T : A = V^T rows (d-major), B = P (lane's own q row, keys kf*32+g*8..+7)
    s16x8 pa[2];
#pragma unroll
    for (int kf = 0; kf < 2; ++kf)
      pa[kf] = *(const s16x8*)((char*)Ps + prow * 128 + (((kf * 4 + g) ^ q7) << 4));
    __builtin_amdgcn_s_setprio(1);
#pragma unroll
    for (int f = 0; f < 4; ++f) {
      const int vrow = f * 16 + q15;
      const int v7 = vrow & 7;
#pragma unroll
      for (int kf = 0; kf < 2; ++kf) {
        const s16x8 vb = *(const s16x8*)&Vts[buf][vrow * 64 + (((kf * 4 + g) ^ v7) << 3)];
        o[f] = mfma16(vb, pa[kf], o[f]);
      }
    }
    __builtin_amdgcn_s_setprio(0);

    // drain our ds_reads before anyone overwrites this buffer next iteration
    asm volatile("s_waitcnt lgkmcnt(0)" ::: "memory");
    __builtin_amdgcn_s_barrier();
  }

  const int qrow = qbase + wv * 16 + q15;
  if (qrow < qend) {
    const float inv = 1.0f / lrow;
    unsigned short* op = og + ((long)b * N_ + qrow) * 768 + h * 64 + g * 4;
#pragma unroll
    for (int f = 0; f < 4; ++f) {
      uint2 ow;
      ow.x = cvt_pk_bf16(o[f][0] * inv, o[f][1] * inv);
      ow.y = cvt_pk_bf16(o[f][2] * inv, o[f][3] * inv);
      *(uint2*)(op + f * 16) = ow;     // 8B store, d = f*16 + g*4 .. +3
    }
  }
}

extern "C" void kernel_launch(void* const* d_in, const int* in_sizes, int n_in,
                              void* d_out, int out_size, void* d_ws, size_t ws_size,
                              hipStream_t stream) {
  const float* x      = (const float*)d_in[0];
  const float* W_qkv  = (const float*)d_in[1];
  const float* b_qkv  = (const float*)d_in[2];
  const float* W_proj = (const float*)d_in[3];
  const float* b_proj = (const float*)d_in[4];
  float* out = (float*)d_out;

  unsigned short* ws = (unsigned short*)d_ws;
  unsigned short* wqkvT  = ws;                                  // [2304][768] bf16
  unsigned short* wprojT = wqkvT + (long)2304 * 768;            // [768][768] bf16
  unsigned short* qb = wprojT + (long)768 * 768;                // [B][H][1024][64] bf16
  const long kvsz = (long)B_ * H_ * NKV_ * D_;
  unsigned short* kb = qb + kvsz;                               // [B][H][1024][64] bf16
  unsigned short* vb = kb + kvsz;                               // V^T: [B][H][64][1024] bf16
  unsigned short* xb = vb + kvsz;                               // [MPAD][768] bf16
  unsigned short* attnout = xb;  // aliased: xb dead after QKV GEMM (stream-ordered)

  zero_pad<<<1440, 256, 0, stream>>>(kb, vb);
  convert_x<<<12144, 256, 0, stream>>>(x, xb);
  transpose_convert<<<dim3(2304 / 64, 768 / 64), 256, 0, stream>>>(W_qkv, wqkvT, 768, 2304);
  transpose_convert<<<dim3(768 / 64, 768 / 64), 256, 0, stream>>>(W_proj, wprojT, 768, 768);
  gemm_bt<0><<<MT_ * 18, 256, 0, stream>>>(xb, wqkvT, b_qkv, qb, kb, vb, nullptr);
  misc_copy<<<96, 256, 0, stream>>>(vb, attnout);
  attn_kernel<<<B_ * H_ * 16, 256, 0, stream>>>(qb, kb, vb, attnout);
  gemm_bt<1><<<MT_ * 6, 256, 0, stream>>>(attnout, wprojT, b_proj, nullptr, nullptr, nullptr, out);
}